// Round 1
// baseline (435.589 us; speedup 1.0000x reference)
//
#include <hip/hip_runtime.h>
#include <hip/hip_bf16.h>

typedef __bf16 bf16x8 __attribute__((ext_vector_type(8)));
typedef float f32x4 __attribute__((ext_vector_type(4)));
typedef unsigned short u16x4 __attribute__((ext_vector_type(4)));
typedef unsigned short u16x8 __attribute__((ext_vector_type(8)));

#define B_ 4
#define S_ 2048
#define D_ 1024
#define H_ 16
#define HD_ 64

__device__ __forceinline__ unsigned short f2bf(float f) {
  unsigned u = __float_as_uint(f);
  u += 0x7fff + ((u >> 16) & 1);   // round-to-nearest-even
  return (unsigned short)(u >> 16);
}

__device__ __forceinline__ void gload16(const void* g, void* l) {
  __builtin_amdgcn_global_load_lds((const __attribute__((address_space(1))) unsigned int*)g,
                                   (__attribute__((address_space(3))) unsigned int*)l,
                                   16, 0, 0);
}

// ---------------- pack kernels ----------------
__global__ void pack_x_k(const float* __restrict__ in, unsigned short* __restrict__ out, int n4) {
  int i = blockIdx.x * blockDim.x + threadIdx.x;
  int stride = gridDim.x * blockDim.x;
  for (; i < n4; i += stride) {
    float4 v = reinterpret_cast<const float4*>(in)[i];
    u16x4 o = {f2bf(v.x), f2bf(v.y), f2bf(v.z), f2bf(v.w)};
    reinterpret_cast<u16x4*>(out)[i] = o;
  }
}

// Wq/Wk/Wv [H][D][HD] f32 -> Wt [3*D][D] bf16, Wt[h*64+e (+1024/2048)][d] = W[h][d][e]
__global__ void pack_wqkv_k(const float* __restrict__ Wq, const float* __restrict__ Wk,
                            const float* __restrict__ Wv, unsigned short* __restrict__ Wt) {
  int o = blockIdx.x * blockDim.x + threadIdx.x;  // 0 .. 3*1024*1024-1
  int n = o >> 10;
  int d = o & 1023;
  const float* W = (n < 1024) ? Wq : (n < 2048) ? Wk : Wv;
  int nn = n & 1023;
  int h = nn >> 6, e = nn & 63;
  Wt[o] = f2bf(W[(h << 16) + (d << 6) + e]);
}

// ---------------- GEMM: C[M][N] = A[M][K] * Bt[N][K]^T ----------------
template <int ADD_BIAS>
__global__ __launch_bounds__(256, 2) void gemm_bt_k(const unsigned short* __restrict__ A,
                                                    const unsigned short* __restrict__ Bt,
                                                    void* __restrict__ C,
                                                    const float* __restrict__ bias,
                                                    int M, int N, int K) {
  __shared__ __align__(16) unsigned short lA[2][128 * 64];
  __shared__ __align__(16) unsigned short lB[2][128 * 64];
  const int tid = threadIdx.x;
  const int wid = tid >> 6, lane = tid & 63;
  const int r = lane & 15, g = lane >> 4;
  const long arow0 = (long)blockIdx.x * 128;
  const long brow0 = (long)blockIdx.y * 128;
  const int wr = (wid >> 1) * 64, wc = (wid & 1) * 64;

  const f32x4 z4 = {0.f, 0.f, 0.f, 0.f};
  f32x4 acc[4][4];
#pragma unroll
  for (int m = 0; m < 4; ++m)
#pragma unroll
    for (int n = 0; n < 4; ++n) acc[m][n] = z4;

  auto stage = [&](int buf, int k0) {
#pragma unroll
    for (int c = 0; c < 4; ++c) {
      const int j = c * 256 + wid * 64 + lane;   // 16B chunk id, 0..1023
      const int row = j >> 3, col = (j & 7) * 8; // 8 chunks per 64-elem row
      gload16(A + (arow0 + row) * K + k0 + col, &lA[buf][(c * 256 + wid * 64) * 8]);
      gload16(Bt + (brow0 + row) * K + k0 + col, &lB[buf][(c * 256 + wid * 64) * 8]);
    }
  };

  stage(0, 0);
  __syncthreads();
  const int nk = K >> 6;
  for (int kt = 0; kt < nk; ++kt) {
    const int cur = kt & 1;
    if (kt + 1 < nk) stage(cur ^ 1, (kt + 1) << 6);
#pragma unroll
    for (int kk = 0; kk < 2; ++kk) {
      bf16x8 af[4], bfr[4];
#pragma unroll
      for (int m = 0; m < 4; ++m)
        af[m] = *(const bf16x8*)&lA[cur][(wr + m * 16 + r) * 64 + kk * 32 + g * 8];
#pragma unroll
      for (int n = 0; n < 4; ++n)
        bfr[n] = *(const bf16x8*)&lB[cur][(wc + n * 16 + r) * 64 + kk * 32 + g * 8];
#pragma unroll
      for (int m = 0; m < 4; ++m)
#pragma unroll
        for (int n = 0; n < 4; ++n)
          acc[m][n] = __builtin_amdgcn_mfma_f32_16x16x32_bf16(af[m], bfr[n], acc[m][n], 0, 0, 0);
    }
    __syncthreads();
  }

#pragma unroll
  for (int m = 0; m < 4; ++m) {
#pragma unroll
    for (int n = 0; n < 4; ++n) {
#pragma unroll
      for (int rr = 0; rr < 4; ++rr) {
        const long row = arow0 + wr + m * 16 + g * 4 + rr;
        const long col = brow0 + wc + n * 16 + r;
        const float v = acc[m][n][rr];
        if (ADD_BIAS) {
          ((float*)C)[row * N + col] = v + bias[col];
        } else {
          ((unsigned short*)C)[row * N + col] = f2bf(v);
        }
      }
    }
  }
}

// ---------------- flash attention ----------------
// qkv: [B*S][3072] bf16 (q|k|v each [H=16][HD=64] concat), out: [B*S][1024] bf16
__global__ __launch_bounds__(256, 4) void attn_k(const unsigned short* __restrict__ qkv,
                                                 unsigned short* __restrict__ out) {
  __shared__ __align__(16) unsigned short lK[64 * 64];
  __shared__ __align__(16) unsigned short lVt[64 * 64];
  __shared__ __align__(16) unsigned short lP[4][16 * 64];

  const int tid = threadIdx.x, wid = tid >> 6, lane = tid & 63;
  const int r = lane & 15, g = lane >> 4;
  const int q0 = blockIdx.x * 64;
  const int bh = blockIdx.y;
  const int b = bh >> 4, h = bh & 15;

  const long base = ((long)b * S_) * 3072 + h * 64;
  const unsigned short* Qg = qkv + base;
  const unsigned short* Kg = qkv + base + 1024;
  const unsigned short* Vg = qkv + base + 2048;

  // hoist Q fragments (A-operand: lane holds Q[l&15][8*(l>>4)+i] per 32-K step)
  const int qrow = q0 + wid * 16 + r;
  bf16x8 qf[2];
#pragma unroll
  for (int kk = 0; kk < 2; ++kk)
    qf[kk] = *(const bf16x8*)&Qg[(long)qrow * 3072 + kk * 32 + g * 8];

  const f32x4 z4 = {0.f, 0.f, 0.f, 0.f};
  f32x4 o[4];
#pragma unroll
  for (int nt = 0; nt < 4; ++nt) o[nt] = z4;
  float m_i[4], l_i[4];
#pragma unroll
  for (int rr = 0; rr < 4; ++rr) {
    m_i[rr] = -INFINITY;
    l_i[rr] = 0.f;
  }

  const int ntiles = (q0 >> 6) + 1;  // causal: only tiles with t0 <= q0
  for (int t = 0; t < ntiles; ++t) {
    const int t0 = t << 6;
    // stage K [64 t][64 e], LDS-linear chunks
#pragma unroll
    for (int c = 0; c < 2; ++c) {
      const int j = c * 256 + tid;
      const int tt = j >> 3, e0 = (j & 7) * 8;
      *(u16x8*)&lK[j * 8] = *(const u16x8*)&Kg[(long)(t0 + tt) * 3072 + e0];
    }
    // stage V transposed: lVt[e][t] = V[t][e]
#pragma unroll
    for (int c = 0; c < 2; ++c) {
      const int j = c * 256 + tid;
      const int tc = j & 63, ec = j >> 6;
      u16x8 v = *(const u16x8*)&Vg[(long)(t0 + tc) * 3072 + ec * 8];
#pragma unroll
      for (int i = 0; i < 8; ++i) lVt[(ec * 8 + i) * 64 + tc] = v[i];
    }
    __syncthreads();

    // S = Q K^T  (4 t-tiles of 16 cols)
    f32x4 st[4];
#pragma unroll
    for (int tt = 0; tt < 4; ++tt) st[tt] = z4;
#pragma unroll
    for (int kk = 0; kk < 2; ++kk)
#pragma unroll
      for (int tt = 0; tt < 4; ++tt) {
        bf16x8 kf = *(const bf16x8*)&lK[(tt * 16 + r) * 64 + kk * 32 + g * 8];
        st[tt] = __builtin_amdgcn_mfma_f32_16x16x32_bf16(qf[kk], kf, st[tt], 0, 0, 0);
      }

    const bool diag = (t == ntiles - 1);
#pragma unroll
    for (int rr = 0; rr < 4; ++rr) {
      const int qr = q0 + wid * 16 + g * 4 + rr;  // output-row q index
      float sv[4];
      float mx = m_i[rr];
#pragma unroll
      for (int tt = 0; tt < 4; ++tt) {
        float s = st[tt][rr] * 0.125f;  // 1/sqrt(64)
        if (diag && (t0 + tt * 16 + r > qr)) s = -INFINITY;
        sv[tt] = s;
        mx = fmaxf(mx, s);
      }
#pragma unroll
      for (int off = 8; off >= 1; off >>= 1) mx = fmaxf(mx, __shfl_xor(mx, off, 64));
      const float corr = __expf(m_i[rr] - mx);
      m_i[rr] = mx;
      float rs = 0.f;
#pragma unroll
      for (int tt = 0; tt < 4; ++tt) {
        const float p = __expf(sv[tt] - mx);
        rs += p;
        lP[wid][(g * 4 + rr) * 64 + tt * 16 + r] = f2bf(p);
      }
#pragma unroll
      for (int off = 8; off >= 1; off >>= 1) rs += __shfl_xor(rs, off, 64);
      l_i[rr] = l_i[rr] * corr + rs;
#pragma unroll
      for (int nt = 0; nt < 4; ++nt) o[nt][rr] *= corr;
    }
    asm volatile("s_waitcnt lgkmcnt(0)" ::: "memory");

    // O += P V
#pragma unroll
    for (int kk = 0; kk < 2; ++kk) {
      const bf16x8 pf = *(const bf16x8*)&lP[wid][r * 64 + kk * 32 + g * 8];
#pragma unroll
      for (int nt = 0; nt < 4; ++nt) {
        const bf16x8 vf = *(const bf16x8*)&lVt[(nt * 16 + r) * 64 + kk * 32 + g * 8];
        o[nt] = __builtin_amdgcn_mfma_f32_16x16x32_bf16(pf, vf, o[nt], 0, 0, 0);
      }
    }
    __syncthreads();
  }

#pragma unroll
  for (int nt = 0; nt < 4; ++nt)
#pragma unroll
    for (int rr = 0; rr < 4; ++rr) {
      const long s = q0 + wid * 16 + g * 4 + rr;
      out[((long)b * S_ + s) * 1024 + h * 64 + nt * 16 + r] = f2bf(o[nt][rr] / l_i[rr]);
    }
}

extern "C" void kernel_launch(void* const* d_in, const int* in_sizes, int n_in,
                              void* d_out, int out_size, void* d_ws, size_t ws_size,
                              hipStream_t stream) {
  const float* x = (const float*)d_in[0];
  const float* Wq = (const float*)d_in[1];
  const float* Wk = (const float*)d_in[2];
  const float* Wv = (const float*)d_in[3];
  const float* Wo = (const float*)d_in[4];
  const float* bo = (const float*)d_in[5];
  float* out = (float*)d_out;

  char* ws = (char*)d_ws;
  unsigned short* Xb = (unsigned short*)(ws);                        // 16 MiB: x bf16 [8192][1024]
  unsigned short* Wt = (unsigned short*)(ws + (16ul << 20));         //  6 MiB: qkv weight B^T [3072][1024]
  unsigned short* Wob = (unsigned short*)(ws + (22ul << 20));        //  2 MiB: Wo bf16 [1024][1024]
  unsigned short* QKV = (unsigned short*)(ws + (24ul << 20));        // 48 MiB: [8192][3072]
  unsigned short* AO = (unsigned short*)(ws + (72ul << 20));         // 16 MiB: attn out [8192][1024]

  pack_x_k<<<2048, 256, 0, stream>>>(x, Xb, (B_ * S_ * D_) / 4);
  pack_x_k<<<512, 256, 0, stream>>>(Wo, Wob, (D_ * D_) / 4);
  pack_wqkv_k<<<(3 * D_ * D_) / 256, 256, 0, stream>>>(Wq, Wk, Wv, Wt);

  gemm_bt_k<0><<<dim3(64, 24), 256, 0, stream>>>(Xb, Wt, QKV, nullptr, B_ * S_, 3 * D_, D_);
  attn_k<<<dim3(S_ / 64, B_ * H_), 256, 0, stream>>>(QKV, AO);
  gemm_bt_k<1><<<dim3(64, 8), 256, 0, stream>>>(AO, Wob, out, bo, B_ * S_, D_, D_);
}

// Round 2
// 350.049 us; speedup vs baseline: 1.2444x; 1.2444x over previous
//
#include <hip/hip_runtime.h>
#include <hip/hip_bf16.h>

typedef __bf16 bf16x8 __attribute__((ext_vector_type(8)));
typedef float f32x4 __attribute__((ext_vector_type(4)));
typedef unsigned short u16x4 __attribute__((ext_vector_type(4)));
typedef unsigned short u16x8 __attribute__((ext_vector_type(8)));

#define B_ 4
#define S_ 2048
#define D_ 1024
#define H_ 16
#define HD_ 64

__device__ __forceinline__ unsigned short f2bf(float f) {
  unsigned u = __float_as_uint(f);
  u += 0x7fff + ((u >> 16) & 1);   // round-to-nearest-even
  return (unsigned short)(u >> 16);
}

__device__ __forceinline__ void gload16(const void* g, void* l) {
  __builtin_amdgcn_global_load_lds((const __attribute__((address_space(1))) unsigned int*)g,
                                   (__attribute__((address_space(3))) unsigned int*)l,
                                   16, 0, 0);
}

// ---------------- pack kernels ----------------
__global__ void pack_x_k(const float* __restrict__ in, unsigned short* __restrict__ out, int n4) {
  int i = blockIdx.x * blockDim.x + threadIdx.x;
  int stride = gridDim.x * blockDim.x;
  for (; i < n4; i += stride) {
    float4 v = reinterpret_cast<const float4*>(in)[i];
    u16x4 o = {f2bf(v.x), f2bf(v.y), f2bf(v.z), f2bf(v.w)};
    reinterpret_cast<u16x4*>(out)[i] = o;
  }
}

// Wq/Wk/Wv [H][D][HD] f32 -> Wt [3*D][D] bf16, Wt[h*64+e (+1024/2048)][d] = W[h][d][e]
__global__ void pack_wqkv_k(const float* __restrict__ Wq, const float* __restrict__ Wk,
                            const float* __restrict__ Wv, unsigned short* __restrict__ Wt) {
  int o = blockIdx.x * blockDim.x + threadIdx.x;  // 0 .. 3*1024*1024-1
  int n = o >> 10;
  int d = o & 1023;
  const float* W = (n < 1024) ? Wq : (n < 2048) ? Wk : Wv;
  int nn = n & 1023;
  int h = nn >> 6, e = nn & 63;
  Wt[o] = f2bf(W[(h << 16) + (d << 6) + e]);
}

// ---------------- GEMM: C[M][N] = A[M][K] * Bt[N][K]^T ----------------
template <int ADD_BIAS>
__global__ __launch_bounds__(256, 2) void gemm_bt_k(const unsigned short* __restrict__ A,
                                                    const unsigned short* __restrict__ Bt,
                                                    void* __restrict__ C,
                                                    const float* __restrict__ bias,
                                                    int M, int N, int K) {
  __shared__ __align__(16) unsigned short lA[2][128 * 64];
  __shared__ __align__(16) unsigned short lB[2][128 * 64];
  const int tid = threadIdx.x;
  const int wid = tid >> 6, lane = tid & 63;
  const int r = lane & 15, g = lane >> 4;
  const long arow0 = (long)blockIdx.x * 128;
  const long brow0 = (long)blockIdx.y * 128;
  const int wr = (wid >> 1) * 64, wc = (wid & 1) * 64;

  const f32x4 z4 = {0.f, 0.f, 0.f, 0.f};
  f32x4 acc[4][4];
#pragma unroll
  for (int m = 0; m < 4; ++m)
#pragma unroll
    for (int n = 0; n < 4; ++n) acc[m][n] = z4;

  auto stage = [&](int buf, int k0) {
#pragma unroll
    for (int c = 0; c < 4; ++c) {
      const int j = c * 256 + wid * 64 + lane;   // 16B chunk id, 0..1023
      const int row = j >> 3, col = (j & 7) * 8; // 8 chunks per 64-elem row
      gload16(A + (arow0 + row) * K + k0 + col, &lA[buf][(c * 256 + wid * 64) * 8]);
      gload16(Bt + (brow0 + row) * K + k0 + col, &lB[buf][(c * 256 + wid * 64) * 8]);
    }
  };

  stage(0, 0);
  __syncthreads();
  const int nk = K >> 6;
  for (int kt = 0; kt < nk; ++kt) {
    const int cur = kt & 1;
    if (kt + 1 < nk) stage(cur ^ 1, (kt + 1) << 6);
#pragma unroll
    for (int kk = 0; kk < 2; ++kk) {
      bf16x8 af[4], bfr[4];
#pragma unroll
      for (int m = 0; m < 4; ++m)
        af[m] = *(const bf16x8*)&lA[cur][(wr + m * 16 + r) * 64 + kk * 32 + g * 8];
#pragma unroll
      for (int n = 0; n < 4; ++n)
        bfr[n] = *(const bf16x8*)&lB[cur][(wc + n * 16 + r) * 64 + kk * 32 + g * 8];
#pragma unroll
      for (int m = 0; m < 4; ++m)
#pragma unroll
        for (int n = 0; n < 4; ++n)
          acc[m][n] = __builtin_amdgcn_mfma_f32_16x16x32_bf16(af[m], bfr[n], acc[m][n], 0, 0, 0);
    }
    __syncthreads();
  }

#pragma unroll
  for (int m = 0; m < 4; ++m) {
#pragma unroll
    for (int n = 0; n < 4; ++n) {
#pragma unroll
      for (int rr = 0; rr < 4; ++rr) {
        const long row = arow0 + wr + m * 16 + g * 4 + rr;
        const long col = brow0 + wc + n * 16 + r;
        const float v = acc[m][n][rr];
        if (ADD_BIAS) {
          ((float*)C)[row * N + col] = v + bias[col];
        } else {
          ((unsigned short*)C)[row * N + col] = f2bf(v);
        }
      }
    }
  }
}

// ---------------- flash attention ----------------
// qkv: [B*S][3072] bf16 (q|k|v each [H=16][HD=64] concat), out: [B*S][1024] bf16
// LDS tiles are 64x64 bf16 (128 B rows). All tiles use the T2 XOR swizzle:
// 16B chunk cc within a row is stored at cc ^ (row&7)  (byte ^= (row&7)<<4).
__global__ __launch_bounds__(256, 4) void attn_k(const unsigned short* __restrict__ qkv,
                                                 unsigned short* __restrict__ out) {
  __shared__ __align__(16) unsigned short lK[2][64 * 64];
  __shared__ __align__(16) unsigned short lVt[2][64 * 64];
  __shared__ __align__(16) unsigned short lP[4][16 * 64];

  const int tid = threadIdx.x, wid = tid >> 6, lane = tid & 63;
  const int r = lane & 15, g = lane >> 4;
  const int q0 = (gridDim.x - 1 - blockIdx.x) * 64;  // long blocks dispatch first
  const int bh = blockIdx.y;
  const int b = bh >> 4, h = bh & 15;

  const long base = ((long)b * S_) * 3072 + h * 64;
  const unsigned short* Qg = qkv + base;
  const unsigned short* Kg = qkv + base + 1024;
  const unsigned short* Vg = qkv + base + 2048;

  // hoist Q fragments (A-operand: lane holds Q[l&15][8*(l>>4)+i] per 32-K step)
  const int qrow = q0 + wid * 16 + r;
  bf16x8 qf[2];
#pragma unroll
  for (int kk = 0; kk < 2; ++kk)
    qf[kk] = *(const bf16x8*)&Qg[(long)qrow * 3072 + kk * 32 + g * 8];

  const f32x4 z4 = {0.f, 0.f, 0.f, 0.f};
  f32x4 o[4];
#pragma unroll
  for (int nt = 0; nt < 4; ++nt) o[nt] = z4;
  float m_i[4], l_i[4];
#pragma unroll
  for (int rr = 0; rr < 4; ++rr) {
    m_i[rr] = -INFINITY;
    l_i[rr] = 0.f;
  }

  // double-buffer staging registers
  u16x8 kreg[2], vreg[2];
  auto load_regs = [&](int t0) {
#pragma unroll
    for (int c = 0; c < 2; ++c) {
      const int j = c * 256 + tid;
      const int tt = j >> 3, e0 = (j & 7) * 8;   // K: row tt, chunk e0/8
      kreg[c] = *(const u16x8*)&Kg[(long)(t0 + tt) * 3072 + e0];
      const int tc = j & 63, ec = j >> 6;        // V: token tc, elems ec*8..
      vreg[c] = *(const u16x8*)&Vg[(long)(t0 + tc) * 3072 + ec * 8];
    }
  };
  auto write_lds = [&](int buf) {
#pragma unroll
    for (int c = 0; c < 2; ++c) {
      const int j = c * 256 + tid;
      const int row = j >> 3, cc = j & 7;
      *(u16x8*)&lK[buf][(row * 8 + (cc ^ (row & 7))) * 8] = kreg[c];
      const int tc = j & 63, ec = j >> 6;
#pragma unroll
      for (int i = 0; i < 8; ++i) {
        const int e = ec * 8 + i;                 // lVt row = feature e, col = token tc
        lVt[buf][e * 64 + (tc ^ (i * 8))] = vreg[c][i];
      }
    }
  };

  const int ntiles = (q0 >> 6) + 1;  // causal: only tiles with t0 <= q0
  load_regs(0);
  write_lds(0);

  for (int t = 0; t < ntiles; ++t) {
    const int cur = t & 1;
    if (t + 1 < ntiles) load_regs((t + 1) << 6);  // issue early: latency hides under compute
    __syncthreads();                              // LDS[cur] ready; prior reads of cur^1 done

    const int t0 = t << 6;
    // S = Q K^T  (4 t-tiles of 16 cols); swizzled lK reads
    f32x4 st[4];
#pragma unroll
    for (int tt = 0; tt < 4; ++tt) st[tt] = z4;
#pragma unroll
    for (int kk = 0; kk < 2; ++kk)
#pragma unroll
      for (int tt = 0; tt < 4; ++tt) {
        const int row = tt * 16 + r, cc = kk * 4 + g;
        bf16x8 kf = *(const bf16x8*)&lK[cur][(row * 8 + (cc ^ (row & 7))) * 8];
        st[tt] = __builtin_amdgcn_mfma_f32_16x16x32_bf16(qf[kk], kf, st[tt], 0, 0, 0);
      }

    const bool diag = (t == ntiles - 1);
#pragma unroll
    for (int rr = 0; rr < 4; ++rr) {
      const int prow = g * 4 + rr;                // q row within wave's 16
      const int qr = q0 + wid * 16 + prow;        // global q index
      float sv[4];
      float mx = m_i[rr];
#pragma unroll
      for (int tt = 0; tt < 4; ++tt) {
        float s = st[tt][rr] * 0.125f;  // 1/sqrt(64)
        if (diag && (t0 + tt * 16 + r > qr)) s = -INFINITY;
        sv[tt] = s;
        mx = fmaxf(mx, s);
      }
#pragma unroll
      for (int off = 8; off >= 1; off >>= 1) mx = fmaxf(mx, __shfl_xor(mx, off, 64));
      const float corr = __expf(m_i[rr] - mx);
      m_i[rr] = mx;
      float rs = 0.f;
#pragma unroll
      for (int tt = 0; tt < 4; ++tt) {
        const float p = __expf(sv[tt] - mx);
        rs += p;
        lP[wid][prow * 64 + ((tt * 16 + r) ^ ((prow & 7) * 8))] = f2bf(p);
      }
#pragma unroll
      for (int off = 8; off >= 1; off >>= 1) rs += __shfl_xor(rs, off, 64);
      l_i[rr] = l_i[rr] * corr + rs;
#pragma unroll
      for (int nt = 0; nt < 4; ++nt) o[nt][rr] *= corr;
    }
    asm volatile("s_waitcnt lgkmcnt(0)" ::: "memory");

    // O += P V   (swizzled lP / lVt reads)
#pragma unroll
    for (int kk = 0; kk < 2; ++kk) {
      const int pcc = kk * 4 + g;
      const bf16x8 pf = *(const bf16x8*)&lP[wid][(r * 8 + (pcc ^ (r & 7))) * 8];
#pragma unroll
      for (int nt = 0; nt < 4; ++nt) {
        const int row = nt * 16 + r, cc = kk * 4 + g;
        const bf16x8 vf = *(const bf16x8*)&lVt[cur][(row * 8 + (cc ^ (row & 7))) * 8];
        o[nt] = __builtin_amdgcn_mfma_f32_16x16x32_bf16(pf, vf, o[nt], 0, 0, 0);
      }
    }

    if (t + 1 < ntiles) write_lds(cur ^ 1);  // safe: all waves passed this tile's barrier
  }

#pragma unroll
  for (int nt = 0; nt < 4; ++nt)
#pragma unroll
    for (int rr = 0; rr < 4; ++rr) {
      const long s = q0 + wid * 16 + g * 4 + rr;
      out[((long)b * S_ + s) * 1024 + h * 64 + nt * 16 + r] = f2bf(o[nt][rr] / l_i[rr]);
    }
}

extern "C" void kernel_launch(void* const* d_in, const int* in_sizes, int n_in,
                              void* d_out, int out_size, void* d_ws, size_t ws_size,
                              hipStream_t stream) {
  const float* x = (const float*)d_in[0];
  const float* Wq = (const float*)d_in[1];
  const float* Wk = (const float*)d_in[2];
  const float* Wv = (const float*)d_in[3];
  const float* Wo = (const float*)d_in[4];
  const float* bo = (const float*)d_in[5];
  float* out = (float*)d_out;

  char* ws = (char*)d_ws;
  unsigned short* Xb = (unsigned short*)(ws);                        // 16 MiB: x bf16 [8192][1024]
  unsigned short* Wt = (unsigned short*)(ws + (16ul << 20));         //  6 MiB: qkv weight B^T [3072][1024]
  unsigned short* Wob = (unsigned short*)(ws + (22ul << 20));        //  2 MiB: Wo bf16 [1024][1024]
  unsigned short* QKV = (unsigned short*)(ws + (24ul << 20));        // 48 MiB: [8192][3072]
  unsigned short* AO = (unsigned short*)(ws + (72ul << 20));         // 16 MiB: attn out [8192][1024]

  pack_x_k<<<2048, 256, 0, stream>>>(x, Xb, (B_ * S_ * D_) / 4);
  pack_x_k<<<512, 256, 0, stream>>>(Wo, Wob, (D_ * D_) / 4);
  pack_wqkv_k<<<(3 * D_ * D_) / 256, 256, 0, stream>>>(Wq, Wk, Wv, Wt);

  gemm_bt_k<0><<<dim3(64, 24), 256, 0, stream>>>(Xb, Wt, QKV, nullptr, B_ * S_, 3 * D_, D_);
  attn_k<<<dim3(S_ / 64, B_ * H_), 256, 0, stream>>>(QKV, AO);
  gemm_bt_k<1><<<dim3(64, 8), 256, 0, stream>>>(AO, Wob, out, bo, B_ * S_, D_, D_);
}

// Round 3
// 275.661 us; speedup vs baseline: 1.5802x; 1.2699x over previous
//
#include <hip/hip_runtime.h>
#include <hip/hip_bf16.h>

typedef __bf16 bf16x8 __attribute__((ext_vector_type(8)));
typedef float f32x4 __attribute__((ext_vector_type(4)));
typedef unsigned short u16x4 __attribute__((ext_vector_type(4)));
typedef unsigned short u16x8 __attribute__((ext_vector_type(8)));

#define B_ 4
#define S_ 2048
#define D_ 1024
#define H_ 16
#define HD_ 64

__device__ __forceinline__ unsigned short f2bf(float f) {
  unsigned u = __float_as_uint(f);
  u += 0x7fff + ((u >> 16) & 1);   // round-to-nearest-even
  return (unsigned short)(u >> 16);
}

__device__ __forceinline__ void gload16(const void* g, void* l) {
  __builtin_amdgcn_global_load_lds((const __attribute__((address_space(1))) unsigned int*)g,
                                   (__attribute__((address_space(3))) unsigned int*)l,
                                   16, 0, 0);
}

// ---------------- pack kernels ----------------
__global__ void pack_x_k(const float* __restrict__ in, unsigned short* __restrict__ out, int n4) {
  int i = blockIdx.x * blockDim.x + threadIdx.x;
  int stride = gridDim.x * blockDim.x;
  for (; i < n4; i += stride) {
    float4 v = reinterpret_cast<const float4*>(in)[i];
    u16x4 o = {f2bf(v.x), f2bf(v.y), f2bf(v.z), f2bf(v.w)};
    reinterpret_cast<u16x4*>(out)[i] = o;
  }
}

// Wq/Wk/Wv [H][D][HD] f32 -> Wt [3*D][D] bf16, Wt[h*64+e (+1024/2048)][d] = W[h][d][e]
__global__ void pack_wqkv_k(const float* __restrict__ Wq, const float* __restrict__ Wk,
                            const float* __restrict__ Wv, unsigned short* __restrict__ Wt) {
  int o = blockIdx.x * blockDim.x + threadIdx.x;  // 0 .. 3*1024*1024-1
  int n = o >> 10;
  int d = o & 1023;
  const float* W = (n < 1024) ? Wq : (n < 2048) ? Wk : Wv;
  int nn = n & 1023;
  int h = nn >> 6, e = nn & 63;
  Wt[o] = f2bf(W[(h << 16) + (d << 6) + e]);
}

// ---------------- GEMM: C[M][N] = A[M][K] * Bt[N][K]^T ----------------
template <int ADD_BIAS>
__global__ __launch_bounds__(256, 2) void gemm_bt_k(const unsigned short* __restrict__ A,
                                                    const unsigned short* __restrict__ Bt,
                                                    void* __restrict__ C,
                                                    const float* __restrict__ bias,
                                                    int M, int N, int K) {
  __shared__ __align__(16) unsigned short lA[2][128 * 64];
  __shared__ __align__(16) unsigned short lB[2][128 * 64];
  const int tid = threadIdx.x;
  const int wid = tid >> 6, lane = tid & 63;
  const int r = lane & 15, g = lane >> 4;
  const long arow0 = (long)blockIdx.x * 128;
  const long brow0 = (long)blockIdx.y * 128;
  const int wr = (wid >> 1) * 64, wc = (wid & 1) * 64;

  const f32x4 z4 = {0.f, 0.f, 0.f, 0.f};
  f32x4 acc[4][4];
#pragma unroll
  for (int m = 0; m < 4; ++m)
#pragma unroll
    for (int n = 0; n < 4; ++n) acc[m][n] = z4;

  auto stage = [&](int buf, int k0) {
#pragma unroll
    for (int c = 0; c < 4; ++c) {
      const int j = c * 256 + wid * 64 + lane;   // 16B chunk id, 0..1023
      const int row = j >> 3, col = (j & 7) * 8; // 8 chunks per 64-elem row
      gload16(A + (arow0 + row) * K + k0 + col, &lA[buf][(c * 256 + wid * 64) * 8]);
      gload16(Bt + (brow0 + row) * K + k0 + col, &lB[buf][(c * 256 + wid * 64) * 8]);
    }
  };

  stage(0, 0);
  __syncthreads();
  const int nk = K >> 6;
  for (int kt = 0; kt < nk; ++kt) {
    const int cur = kt & 1;
    if (kt + 1 < nk) stage(cur ^ 1, (kt + 1) << 6);
#pragma unroll
    for (int kk = 0; kk < 2; ++kk) {
      bf16x8 af[4], bfr[4];
#pragma unroll
      for (int m = 0; m < 4; ++m)
        af[m] = *(const bf16x8*)&lA[cur][(wr + m * 16 + r) * 64 + kk * 32 + g * 8];
#pragma unroll
      for (int n = 0; n < 4; ++n)
        bfr[n] = *(const bf16x8*)&lB[cur][(wc + n * 16 + r) * 64 + kk * 32 + g * 8];
#pragma unroll
      for (int m = 0; m < 4; ++m)
#pragma unroll
        for (int n = 0; n < 4; ++n)
          acc[m][n] = __builtin_amdgcn_mfma_f32_16x16x32_bf16(af[m], bfr[n], acc[m][n], 0, 0, 0);
    }
    __syncthreads();
  }

#pragma unroll
  for (int m = 0; m < 4; ++m) {
#pragma unroll
    for (int n = 0; n < 4; ++n) {
#pragma unroll
      for (int rr = 0; rr < 4; ++rr) {
        const long row = arow0 + wr + m * 16 + g * 4 + rr;
        const long col = brow0 + wc + n * 16 + r;
        const float v = acc[m][n][rr];
        if (ADD_BIAS) {
          ((float*)C)[row * N + col] = v + bias[col];
        } else {
          ((unsigned short*)C)[row * N + col] = f2bf(v);
        }
      }
    }
  }
}

// ---------------- flash attention ----------------
// qkv: [B*S][3072] bf16 (q|k|v each [H=16][HD=64] concat), out: [B*S][1024] bf16
// Swapped QK^T: st = mfma(K_frag, Q_frag) gives S^T (q = lane&15, kv in regs/groups)
// -> per-lane softmax over 16 vals, 2 shuffles per reduce instead of 32 total.
// All LDS tiles use the T2 XOR swizzle: 16B chunk cc within a row stored at cc ^ (row&7).
__global__ __launch_bounds__(256, 4) void attn_k(const unsigned short* __restrict__ qkv,
                                                 unsigned short* __restrict__ out) {
  __shared__ __align__(16) unsigned short lK[2][64 * 64];
  __shared__ __align__(16) unsigned short lVt[2][64 * 64];
  __shared__ __align__(16) unsigned short lP[4][16 * 64];

  const int tid = threadIdx.x, wid = tid >> 6, lane = tid & 63;
  const int r = lane & 15, g = lane >> 4;
  const int q0 = (gridDim.x - 1 - blockIdx.x) * 64;  // long blocks dispatch first
  const int bh = blockIdx.y;
  const int b = bh >> 4, h = bh & 15;

  const long base = ((long)b * S_) * 3072 + h * 64;
  const unsigned short* Qg = qkv + base;
  const unsigned short* Kg = qkv + base + 1024;
  const unsigned short* Vg = qkv + base + 2048;

  // hoist Q fragments: lane holds Q[q0+wid*16+r][kk*32+g*8 .. +7] (valid as A or B frag)
  const int qrow = q0 + wid * 16 + r;
  bf16x8 qf[2];
#pragma unroll
  for (int kk = 0; kk < 2; ++kk)
    qf[kk] = *(const bf16x8*)&Qg[(long)qrow * 3072 + kk * 32 + g * 8];

  const f32x4 z4 = {0.f, 0.f, 0.f, 0.f};
  f32x4 o[4];
#pragma unroll
  for (int nt = 0; nt < 4; ++nt) o[nt] = z4;
  float m_i = -1e30f;  // running max for q-row = q0 + wid*16 + r (per-lane)
  float l_i = 0.f;

  // double-buffer staging registers
  u16x8 kreg[2], vreg[2];
  auto load_regs = [&](int t0) {
#pragma unroll
    for (int c = 0; c < 2; ++c) {
      const int j = c * 256 + tid;
      const int tt = j >> 3, e0 = (j & 7) * 8;   // K: row tt, chunk e0/8
      kreg[c] = *(const u16x8*)&Kg[(long)(t0 + tt) * 3072 + e0];
      const int tc = j & 63, ec = j >> 6;        // V: token tc, elems ec*8..
      vreg[c] = *(const u16x8*)&Vg[(long)(t0 + tc) * 3072 + ec * 8];
    }
  };
  auto write_lds = [&](int buf) {
#pragma unroll
    for (int c = 0; c < 2; ++c) {
      const int j = c * 256 + tid;
      const int row = j >> 3, cc = j & 7;
      *(u16x8*)&lK[buf][(row * 8 + (cc ^ (row & 7))) * 8] = kreg[c];
      const int tc = j & 63, ec = j >> 6;
#pragma unroll
      for (int i = 0; i < 8; ++i) {
        const int e = ec * 8 + i;                 // lVt row = feature e, col = token tc
        lVt[buf][e * 64 + (tc ^ (i * 8))] = vreg[c][i];
      }
    }
  };

  const int ntiles = (q0 >> 6) + 1;  // causal: only tiles with t0 <= q0
  load_regs(0);
  write_lds(0);

  for (int t = 0; t < ntiles; ++t) {
    const int cur = t & 1;
    if (t + 1 < ntiles) load_regs((t + 1) << 6);  // issue early: latency hides under compute
    __syncthreads();                              // LDS[cur] ready; prior reads of cur^1 done

    const int t0 = t << 6;
    // S^T = K Q^T : swapped operands. st[tt][reg] = S[q=qrow][kv=t0+tt*16+4g+reg]
    f32x4 st[4];
#pragma unroll
    for (int tt = 0; tt < 4; ++tt) st[tt] = z4;
    __builtin_amdgcn_s_setprio(1);
#pragma unroll
    for (int kk = 0; kk < 2; ++kk)
#pragma unroll
      for (int tt = 0; tt < 4; ++tt) {
        const int row = tt * 16 + r, cc = kk * 4 + g;
        bf16x8 kf = *(const bf16x8*)&lK[cur][(row * 8 + (cc ^ (row & 7))) * 8];
        st[tt] = __builtin_amdgcn_mfma_f32_16x16x32_bf16(kf, qf[kk], st[tt], 0, 0, 0);
      }
    __builtin_amdgcn_s_setprio(0);

    const bool diag = (t == ntiles - 1);
    // per-lane softmax over this lane's 16 kv values (all for q-row = qrow)
    float sv[16];
    float pmax = -1e30f;
#pragma unroll
    for (int tt = 0; tt < 4; ++tt)
#pragma unroll
      for (int rg = 0; rg < 4; ++rg) {
        float s = st[tt][rg] * 0.125f;  // 1/sqrt(64)
        if (diag && (t0 + tt * 16 + g * 4 + rg > qrow)) s = -1e30f;
        sv[tt * 4 + rg] = s;
        pmax = fmaxf(pmax, s);
      }
    const bool defer = __all(pmax - m_i <= 8.f);  // T13: skip rescale when growth small
    float corr = 1.f;
    if (!defer) {
      float mx = fmaxf(pmax, m_i);
      mx = fmaxf(mx, __shfl_xor(mx, 16, 64));
      mx = fmaxf(mx, __shfl_xor(mx, 32, 64));
      corr = __expf(m_i - mx);
      m_i = mx;
    }
    float rs = 0.f;
    unsigned pk[8];
#pragma unroll
    for (int i = 0; i < 16; i += 2) {
      const float p0 = __expf(sv[i] - m_i);
      const float p1 = __expf(sv[i + 1] - m_i);
      rs += p0 + p1;
      pk[i >> 1] = (unsigned)f2bf(p0) | ((unsigned)f2bf(p1) << 16);
    }
    rs += __shfl_xor(rs, 16, 64);
    rs += __shfl_xor(rs, 32, 64);
    l_i = l_i * corr + rs;
    if (!defer) {
#pragma unroll
      for (int rr = 0; rr < 4; ++rr) {
        const float c = __shfl(corr, (g << 4) | (g * 4 + rr), 64);
#pragma unroll
        for (int nt = 0; nt < 4; ++nt) o[nt][rr] *= c;
      }
    }
    // write P^T to wave-private lP (swizzled), 4 x ds_write_b64:
    // chunk c = kv/8 = 2*tt + (g>>1), in-chunk elem = (g&1)*4
#pragma unroll
    for (int tt = 0; tt < 4; ++tt) {
      uint2 w;
      w.x = pk[2 * tt];
      w.y = pk[2 * tt + 1];
      *(uint2*)&lP[wid][r * 64 + (((2 * tt + (g >> 1)) ^ (r & 7)) << 3) + ((g & 1) << 2)] = w;
    }
    asm volatile("s_waitcnt lgkmcnt(0)" ::: "memory");

    // O += P V   (pf as A from lP, vf as B from lVt; both swizzled)
    __builtin_amdgcn_s_setprio(1);
#pragma unroll
    for (int kk = 0; kk < 2; ++kk) {
      const int pcc = kk * 4 + g;
      const bf16x8 pf = *(const bf16x8*)&lP[wid][(r * 8 + (pcc ^ (r & 7))) * 8];
#pragma unroll
      for (int nt = 0; nt < 4; ++nt) {
        const int row = nt * 16 + r, cc = kk * 4 + g;
        const bf16x8 vf = *(const bf16x8*)&lVt[cur][(row * 8 + (cc ^ (row & 7))) * 8];
        o[nt] = __builtin_amdgcn_mfma_f32_16x16x32_bf16(pf, vf, o[nt], 0, 0, 0);
      }
    }
    __builtin_amdgcn_s_setprio(0);

    if (t + 1 < ntiles) write_lds(cur ^ 1);  // safe: all waves passed this tile's barrier
  }

  // broadcast l for O's rows (q-within-16 = 4g+rr lives at lane (g<<4)|(4g+rr))
  float linv[4];
#pragma unroll
  for (int rr = 0; rr < 4; ++rr)
    linv[rr] = 1.f / __shfl(l_i, (g << 4) | (g * 4 + rr), 64);
#pragma unroll
  for (int nt = 0; nt < 4; ++nt)
#pragma unroll
    for (int rr = 0; rr < 4; ++rr) {
      const long s = q0 + wid * 16 + g * 4 + rr;
      out[((long)b * S_ + s) * 1024 + h * 64 + nt * 16 + r] = f2bf(o[nt][rr] * linv[rr]);
    }
}

extern "C" void kernel_launch(void* const* d_in, const int* in_sizes, int n_in,
                              void* d_out, int out_size, void* d_ws, size_t ws_size,
                              hipStream_t stream) {
  const float* x = (const float*)d_in[0];
  const float* Wq = (const float*)d_in[1];
  const float* Wk = (const float*)d_in[2];
  const float* Wv = (const float*)d_in[3];
  const float* Wo = (const float*)d_in[4];
  const float* bo = (const float*)d_in[5];
  float* out = (float*)d_out;

  char* ws = (char*)d_ws;
  unsigned short* Xb = (unsigned short*)(ws);                        // 16 MiB: x bf16 [8192][1024]
  unsigned short* Wt = (unsigned short*)(ws + (16ul << 20));         //  6 MiB: qkv weight B^T [3072][1024]
  unsigned short* Wob = (unsigned short*)(ws + (22ul << 20));        //  2 MiB: Wo bf16 [1024][1024]
  unsigned short* QKV = (unsigned short*)(ws + (24ul << 20));        // 48 MiB: [8192][3072]
  unsigned short* AO = (unsigned short*)(ws + (72ul << 20));         // 16 MiB: attn out [8192][1024]

  pack_x_k<<<2048, 256, 0, stream>>>(x, Xb, (B_ * S_ * D_) / 4);
  pack_x_k<<<512, 256, 0, stream>>>(Wo, Wob, (D_ * D_) / 4);
  pack_wqkv_k<<<(3 * D_ * D_) / 256, 256, 0, stream>>>(Wq, Wk, Wv, Wt);

  gemm_bt_k<0><<<dim3(64, 24), 256, 0, stream>>>(Xb, Wt, QKV, nullptr, B_ * S_, 3 * D_, D_);
  attn_k<<<dim3(S_ / 64, B_ * H_), 256, 0, stream>>>(QKV, AO);
  gemm_bt_k<1><<<dim3(64, 8), 256, 0, stream>>>(AO, Wob, out, bo, B_ * S_, D_, D_);
}

// Round 4
// 200.400 us; speedup vs baseline: 2.1736x; 1.3756x over previous
//
#include <hip/hip_runtime.h>
#include <hip/hip_bf16.h>

typedef __bf16 bf16x8 __attribute__((ext_vector_type(8)));
typedef float f32x4 __attribute__((ext_vector_type(4)));
typedef unsigned short u16x4 __attribute__((ext_vector_type(4)));
typedef unsigned short u16x8 __attribute__((ext_vector_type(8)));
typedef unsigned uint4v __attribute__((ext_vector_type(4)));

#define B_ 4
#define S_ 2048
#define D_ 1024
#define H_ 16
#define HD_ 64

__device__ __forceinline__ unsigned short f2bf(float f) {
  unsigned u = __float_as_uint(f);
  u += 0x7fff + ((u >> 16) & 1);   // round-to-nearest-even
  return (unsigned short)(u >> 16);
}

__device__ __forceinline__ void gload16(const void* g, void* l) {
  __builtin_amdgcn_global_load_lds((const __attribute__((address_space(1))) unsigned int*)g,
                                   (__attribute__((address_space(3))) unsigned int*)l,
                                   16, 0, 0);
}

// ---------------- pack kernels ----------------
__global__ void pack_x_k(const float* __restrict__ in, unsigned short* __restrict__ out, int n4) {
  int i = blockIdx.x * blockDim.x + threadIdx.x;
  int stride = gridDim.x * blockDim.x;
  for (; i < n4; i += stride) {
    float4 v = reinterpret_cast<const float4*>(in)[i];
    u16x4 o = {f2bf(v.x), f2bf(v.y), f2bf(v.z), f2bf(v.w)};
    reinterpret_cast<u16x4*>(out)[i] = o;
  }
}

// Wq/Wk/Wv [H][D][HD] f32 -> Wt [3*D][D] bf16, Wt[h*64+e (+1024/2048)][d] = W[h][d][e]
__global__ void pack_wqkv_k(const float* __restrict__ Wq, const float* __restrict__ Wk,
                            const float* __restrict__ Wv, unsigned short* __restrict__ Wt) {
  int o = blockIdx.x * blockDim.x + threadIdx.x;  // 0 .. 3*1024*1024-1
  int n = o >> 10;
  int d = o & 1023;
  const float* W = (n < 1024) ? Wq : (n < 2048) ? Wk : Wv;
  int nn = n & 1023;
  int h = nn >> 6, e = nn & 63;
  Wt[o] = f2bf(W[(h << 16) + (d << 6) + e]);
}

// ---------------- GEMM: C[M][N] = A[M][K] * Bt[N][K]^T ----------------
template <int ADD_BIAS>
__global__ __launch_bounds__(256, 2) void gemm_bt_k(const unsigned short* __restrict__ A,
                                                    const unsigned short* __restrict__ Bt,
                                                    void* __restrict__ C,
                                                    const float* __restrict__ bias,
                                                    int M, int N, int K) {
  __shared__ __align__(16) unsigned short lA[2][128 * 64];
  __shared__ __align__(16) unsigned short lB[2][128 * 64];
  const int tid = threadIdx.x;
  const int wid = tid >> 6, lane = tid & 63;
  const int r = lane & 15, g = lane >> 4;
  const long arow0 = (long)blockIdx.x * 128;
  const long brow0 = (long)blockIdx.y * 128;
  const int wr = (wid >> 1) * 64, wc = (wid & 1) * 64;

  const f32x4 z4 = {0.f, 0.f, 0.f, 0.f};
  f32x4 acc[4][4];
#pragma unroll
  for (int m = 0; m < 4; ++m)
#pragma unroll
    for (int n = 0; n < 4; ++n) acc[m][n] = z4;

  auto stage = [&](int buf, int k0) {
#pragma unroll
    for (int c = 0; c < 4; ++c) {
      const int j = c * 256 + wid * 64 + lane;   // 16B chunk id, 0..1023
      const int row = j >> 3, col = (j & 7) * 8; // 8 chunks per 64-elem row
      gload16(A + (arow0 + row) * K + k0 + col, &lA[buf][(c * 256 + wid * 64) * 8]);
      gload16(Bt + (brow0 + row) * K + k0 + col, &lB[buf][(c * 256 + wid * 64) * 8]);
    }
  };

  stage(0, 0);
  __syncthreads();
  const int nk = K >> 6;
  for (int kt = 0; kt < nk; ++kt) {
    const int cur = kt & 1;
    if (kt + 1 < nk) stage(cur ^ 1, (kt + 1) << 6);
#pragma unroll
    for (int kk = 0; kk < 2; ++kk) {
      bf16x8 af[4], bfr[4];
#pragma unroll
      for (int m = 0; m < 4; ++m)
        af[m] = *(const bf16x8*)&lA[cur][(wr + m * 16 + r) * 64 + kk * 32 + g * 8];
#pragma unroll
      for (int n = 0; n < 4; ++n)
        bfr[n] = *(const bf16x8*)&lB[cur][(wc + n * 16 + r) * 64 + kk * 32 + g * 8];
#pragma unroll
      for (int m = 0; m < 4; ++m)
#pragma unroll
        for (int n = 0; n < 4; ++n)
          acc[m][n] = __builtin_amdgcn_mfma_f32_16x16x32_bf16(af[m], bfr[n], acc[m][n], 0, 0, 0);
    }
    __syncthreads();
  }

#pragma unroll
  for (int m = 0; m < 4; ++m) {
#pragma unroll
    for (int n = 0; n < 4; ++n) {
#pragma unroll
      for (int rr = 0; rr < 4; ++rr) {
        const long row = arow0 + wr + m * 16 + g * 4 + rr;
        const long col = brow0 + wc + n * 16 + r;
        const float v = acc[m][n][rr];
        if (ADD_BIAS) {
          ((float*)C)[row * N + col] = v + bias[col];
        } else {
          ((unsigned short*)C)[row * N + col] = f2bf(v);
        }
      }
    }
  }
}

// ---------------- flash attention ----------------
// qkv: [B*S][3072] bf16 (q|k|v each [H=16][HD=64] concat), out: [B*S][1024] bf16
// QBLK=128 per block: each wave owns q-subtiles qs=0 (rows q0..q0+63) and qs=1
// (rows q0+64..q0+127), 16 rows each at q0 + qs*64 + wid*16 + r.
// Swapped QK^T: st = mfma(K_frag, Q_frag) -> per-lane softmax over 16 kv values.
// P^T is repacked to PV A-frags fully in registers: v_cvt_pk_bf16_f32 pairs +
// v_permlane32_swap / v_permlane16_swap (no LDS round-trip).
// Grid is (bh=64, qslot=16), bh fastest, long blocks first -> per-CU causal-depth mix.
__global__ __launch_bounds__(256, 2) void attn_k(const unsigned short* __restrict__ qkv,
                                                 unsigned short* __restrict__ out) {
  __shared__ __align__(16) unsigned short lK[2][64 * 64];
  __shared__ __align__(16) unsigned short lVt[2][64 * 64];

  const int tid = threadIdx.x, wid = tid >> 6, lane = tid & 63;
  const int r = lane & 15, g = lane >> 4;
  const int bh = blockIdx.x;
  const int b = bh >> 4, h = bh & 15;
  const int qb = 15 - (int)blockIdx.y;   // long blocks dispatch first
  const int q0 = qb * 128;

  const long base = ((long)b * S_) * 3072 + h * 64;
  const unsigned short* Qg = qkv + base;
  const unsigned short* Kg = qkv + base + 1024;
  const unsigned short* Vg = qkv + base + 2048;

  // Q fragments for both subtiles
  int qrow[2];
  bf16x8 qf[2][2];
#pragma unroll
  for (int qs = 0; qs < 2; ++qs) {
    qrow[qs] = q0 + qs * 64 + wid * 16 + r;
#pragma unroll
    for (int kk = 0; kk < 2; ++kk)
      qf[qs][kk] = *(const bf16x8*)&Qg[(long)qrow[qs] * 3072 + kk * 32 + g * 8];
  }

  const f32x4 z4 = {0.f, 0.f, 0.f, 0.f};
  f32x4 o[2][4];
#pragma unroll
  for (int qs = 0; qs < 2; ++qs)
#pragma unroll
    for (int nt = 0; nt < 4; ++nt) o[qs][nt] = z4;
  float m_i[2] = {-1e30f, -1e30f};
  float l_i[2] = {0.f, 0.f};

  // double-buffer staging registers
  u16x8 kreg[2], vreg[2];
  auto load_regs = [&](int t0) {
#pragma unroll
    for (int c = 0; c < 2; ++c) {
      const int j = c * 256 + tid;
      const int tt = j >> 3, e0 = (j & 7) * 8;   // K: row tt, chunk e0/8
      kreg[c] = *(const u16x8*)&Kg[(long)(t0 + tt) * 3072 + e0];
      const int tc = j & 63, ec = j >> 6;        // V: token tc, elems ec*8..
      vreg[c] = *(const u16x8*)&Vg[(long)(t0 + tc) * 3072 + ec * 8];
    }
  };
  auto write_lds = [&](int buf) {
#pragma unroll
    for (int c = 0; c < 2; ++c) {
      const int j = c * 256 + tid;
      const int row = j >> 3, cc = j & 7;
      *(u16x8*)&lK[buf][(row * 8 + (cc ^ (row & 7))) * 8] = kreg[c];
      const int tc = j & 63, ec = j >> 6;
#pragma unroll
      for (int i = 0; i < 8; ++i) {
        const int e = ec * 8 + i;                 // lVt row = feature e, col = token tc
        lVt[buf][e * 64 + (tc ^ (i * 8))] = vreg[c][i];
      }
    }
  };

  const int ntiles = (q0 >> 6) + 2;  // kv tiles 0 .. q0/64+1
  load_regs(0);
  write_lds(0);

  for (int t = 0; t < ntiles; ++t) {
    const int cur = t & 1;
    if (t + 1 < ntiles) load_regs((t + 1) << 6);  // issue early: latency hides under compute
    __syncthreads();                              // LDS[cur] ready; prior reads of cur^1 done

    const int t0 = t << 6;
    const bool act0 = (t < ntiles - 1);   // qs=0 rows all < q0+64
    const bool diag0 = (t == ntiles - 2); // t0 == q0
    const bool diag1 = (t == ntiles - 1); // t0 == q0+64

    // S^T = K Q^T (swapped operands): st[qs][tt][rg] = S[qrow[qs]][t0+16tt+4g+rg]
    f32x4 st[2][4];
#pragma unroll
    for (int tt = 0; tt < 4; ++tt) { st[0][tt] = z4; st[1][tt] = z4; }
    __builtin_amdgcn_s_setprio(1);
#pragma unroll
    for (int kk = 0; kk < 2; ++kk)
#pragma unroll
      for (int tt = 0; tt < 4; ++tt) {
        const int row = tt * 16 + r, cc = kk * 4 + g;
        bf16x8 kf = *(const bf16x8*)&lK[cur][(row * 8 + (cc ^ (row & 7))) * 8];
        st[1][tt] = __builtin_amdgcn_mfma_f32_16x16x32_bf16(kf, qf[1][kk], st[1][tt], 0, 0, 0);
        if (act0)
          st[0][tt] = __builtin_amdgcn_mfma_f32_16x16x32_bf16(kf, qf[0][kk], st[0][tt], 0, 0, 0);
      }
    __builtin_amdgcn_s_setprio(0);

    // per-lane softmax + in-register P repack, per active subtile
    bf16x8 pf[2][2];
    unsigned corr_bits[2] = {0x3f800000u, 0x3f800000u};
    bool dodef[2] = {true, true};
#pragma unroll
    for (int qs = 0; qs < 2; ++qs) {
      if (qs == 0 && !act0) continue;
      const bool diag = qs ? diag1 : diag0;
      float sv[16];
#pragma unroll
      for (int tt = 0; tt < 4; ++tt)
#pragma unroll
        for (int rg = 0; rg < 4; ++rg) {
          float s = st[qs][tt][rg] * 0.125f;  // 1/sqrt(64)
          if (diag && (t0 + tt * 16 + g * 4 + rg > qrow[qs])) s = -1e30f;
          sv[tt * 4 + rg] = s;
        }
      float h0 = fmaxf(fmaxf(fmaxf(sv[0], sv[1]), fmaxf(sv[2], sv[3])),
                       fmaxf(fmaxf(sv[4], sv[5]), fmaxf(sv[6], sv[7])));
      float h1 = fmaxf(fmaxf(fmaxf(sv[8], sv[9]), fmaxf(sv[10], sv[11])),
                       fmaxf(fmaxf(sv[12], sv[13]), fmaxf(sv[14], sv[15])));
      const float pmax = fmaxf(h0, h1);
      const bool defer = __all(pmax - m_i[qs] <= 8.f);  // T13
      float corr = 1.f;
      if (!defer) {
        float mx = fmaxf(pmax, m_i[qs]);
        mx = fmaxf(mx, __shfl_xor(mx, 16, 64));
        mx = fmaxf(mx, __shfl_xor(mx, 32, 64));
        corr = __expf(m_i[qs] - mx);
        m_i[qs] = mx;
      }
      dodef[qs] = defer;
      corr_bits[qs] = __float_as_uint(corr);
      float p[16];
      float rs = 0.f;
#pragma unroll
      for (int i = 0; i < 16; ++i) {
        p[i] = __expf(sv[i] - m_i[qs]);
        rs += p[i];
      }
      rs += __shfl_xor(rs, 16, 64);
      rs += __shfl_xor(rs, 32, 64);
      l_i[qs] = l_i[qs] * corr + rs;
      // pack pairs: c[tt][e] covers kv pair (16tt + 4g + 2e)
      unsigned cw[4][2];
#pragma unroll
      for (int tt = 0; tt < 4; ++tt)
#pragma unroll
        for (int e = 0; e < 2; ++e)
          asm("v_cvt_pk_bf16_f32 %0, %1, %2"
              : "=v"(cw[tt][e]) : "v"(p[tt * 4 + 2 * e]), "v"(p[tt * 4 + 2 * e + 1]));
      // redistribute to A-frag words: for kk, (w0,w2)=pl16(pl32(c[2kk][0], c[2kk+1][0])),
      // (w1,w3)=pl16(pl32(c[2kk][1], c[2kk+1][1]))
#pragma unroll
      for (int kk = 0; kk < 2; ++kk) {
        unsigned x0 = cw[2 * kk][0], y0 = cw[2 * kk + 1][0];
        unsigned x1 = cw[2 * kk][1], y1 = cw[2 * kk + 1][1];
        asm volatile("v_permlane32_swap_b32 %0, %1" : "+v"(x0), "+v"(y0));
        asm volatile("v_permlane16_swap_b32 %0, %1" : "+v"(x0), "+v"(y0));
        asm volatile("v_permlane32_swap_b32 %0, %1" : "+v"(x1), "+v"(y1));
        asm volatile("v_permlane16_swap_b32 %0, %1" : "+v"(x1), "+v"(y1));
        uint4v w = {x0, x1, y0, y1};  // kv pairs (8g+0),(8g+2),(8g+4),(8g+6)
        pf[qs][kk] = *(bf16x8*)&w;
      }
    }
    // O rescale (rows live at lanes r'=4g+rr; corr per-lane at r) — only when needed
#pragma unroll
    for (int qs = 0; qs < 2; ++qs) {
      if (qs == 0 && !act0) continue;
      if (!dodef[qs]) {
        const float corr = __uint_as_float(corr_bits[qs]);
#pragma unroll
        for (int rr = 0; rr < 4; ++rr) {
          const float c = __shfl(corr, g * 4 + rr, 64);
#pragma unroll
          for (int nt = 0; nt < 4; ++nt) o[qs][nt][rr] *= c;
        }
      }
    }

    // O += P V
    __builtin_amdgcn_s_setprio(1);
#pragma unroll
    for (int kk = 0; kk < 2; ++kk)
#pragma unroll
      for (int nt = 0; nt < 4; ++nt) {
        const int row = nt * 16 + r, cc = kk * 4 + g;
        const bf16x8 vf = *(const bf16x8*)&lVt[cur][(row * 8 + (cc ^ (row & 7))) * 8];
        o[1][nt] = __builtin_amdgcn_mfma_f32_16x16x32_bf16(pf[1][kk], vf, o[1][nt], 0, 0, 0);
        if (act0)
          o[0][nt] = __builtin_amdgcn_mfma_f32_16x16x32_bf16(pf[0][kk], vf, o[0][nt], 0, 0, 0);
      }
    __builtin_amdgcn_s_setprio(0);

    if (t + 1 < ntiles) write_lds(cur ^ 1);  // safe: all waves passed this tile's barrier
  }

#pragma unroll
  for (int qs = 0; qs < 2; ++qs) {
    float linv[4];
#pragma unroll
    for (int rr = 0; rr < 4; ++rr)
      linv[rr] = 1.f / __shfl(l_i[qs], g * 4 + rr, 64);
#pragma unroll
    for (int nt = 0; nt < 4; ++nt)
#pragma unroll
      for (int rr = 0; rr < 4; ++rr) {
        const long s = q0 + qs * 64 + wid * 16 + g * 4 + rr;
        out[((long)b * S_ + s) * 1024 + h * 64 + nt * 16 + r] = f2bf(o[qs][nt][rr] * linv[rr]);
      }
  }
}

extern "C" void kernel_launch(void* const* d_in, const int* in_sizes, int n_in,
                              void* d_out, int out_size, void* d_ws, size_t ws_size,
                              hipStream_t stream) {
  const float* x = (const float*)d_in[0];
  const float* Wq = (const float*)d_in[1];
  const float* Wk = (const float*)d_in[2];
  const float* Wv = (const float*)d_in[3];
  const float* Wo = (const float*)d_in[4];
  const float* bo = (const float*)d_in[5];
  float* out = (float*)d_out;

  char* ws = (char*)d_ws;
  unsigned short* Xb = (unsigned short*)(ws);                        // 16 MiB: x bf16 [8192][1024]
  unsigned short* Wt = (unsigned short*)(ws + (16ul << 20));         //  6 MiB: qkv weight B^T [3072][1024]
  unsigned short* Wob = (unsigned short*)(ws + (22ul << 20));        //  2 MiB: Wo bf16 [1024][1024]
  unsigned short* QKV = (unsigned short*)(ws + (24ul << 20));        // 48 MiB: [8192][3072]
  unsigned short* AO = (unsigned short*)(ws + (72ul << 20));         // 16 MiB: attn out [8192][1024]

  pack_x_k<<<2048, 256, 0, stream>>>(x, Xb, (B_ * S_ * D_) / 4);
  pack_x_k<<<512, 256, 0, stream>>>(Wo, Wob, (D_ * D_) / 4);
  pack_wqkv_k<<<(3 * D_ * D_) / 256, 256, 0, stream>>>(Wq, Wk, Wv, Wt);

  gemm_bt_k<0><<<dim3(64, 24), 256, 0, stream>>>(Xb, Wt, QKV, nullptr, B_ * S_, 3 * D_, D_);
  attn_k<<<dim3(64, 16), 256, 0, stream>>>(QKV, AO);
  gemm_bt_k<1><<<dim3(64, 8), 256, 0, stream>>>(AO, Wob, out, bo, B_ * S_, D_, D_);
}

// Round 5
// 199.275 us; speedup vs baseline: 2.1859x; 1.0056x over previous
//
#include <hip/hip_runtime.h>
#include <hip/hip_bf16.h>

typedef __bf16 bf16x8 __attribute__((ext_vector_type(8)));
typedef float f32x4 __attribute__((ext_vector_type(4)));
typedef unsigned short u16x4 __attribute__((ext_vector_type(4)));
typedef unsigned short u16x8 __attribute__((ext_vector_type(8)));
typedef unsigned uint4v __attribute__((ext_vector_type(4)));

#define B_ 4
#define S_ 2048
#define D_ 1024
#define H_ 16
#define HD_ 64

__device__ __forceinline__ unsigned short f2bf(float f) {
  unsigned u = __float_as_uint(f);
  u += 0x7fff + ((u >> 16) & 1);   // round-to-nearest-even
  return (unsigned short)(u >> 16);
}

__device__ __forceinline__ void gload16(const void* g, void* l) {
  __builtin_amdgcn_global_load_lds((const __attribute__((address_space(1))) unsigned int*)g,
                                   (__attribute__((address_space(3))) unsigned int*)l,
                                   16, 0, 0);
}

// ---------------- pack kernels ----------------
__global__ void pack_x_k(const float* __restrict__ in, unsigned short* __restrict__ out, int n4) {
  int i = blockIdx.x * blockDim.x + threadIdx.x;
  int stride = gridDim.x * blockDim.x;
  for (; i < n4; i += stride) {
    float4 v = reinterpret_cast<const float4*>(in)[i];
    u16x4 o = {f2bf(v.x), f2bf(v.y), f2bf(v.z), f2bf(v.w)};
    reinterpret_cast<u16x4*>(out)[i] = o;
  }
}

// Wq/Wk/Wv [H][D][HD] f32 -> Wt [3*D][D] bf16, Wt[h*64+e (+1024/2048)][d] = W[h][d][e]
__global__ void pack_wqkv_k(const float* __restrict__ Wq, const float* __restrict__ Wk,
                            const float* __restrict__ Wv, unsigned short* __restrict__ Wt) {
  int o = blockIdx.x * blockDim.x + threadIdx.x;  // 0 .. 3*1024*1024-1
  int n = o >> 10;
  int d = o & 1023;
  const float* W = (n < 1024) ? Wq : (n < 2048) ? Wk : Wv;
  int nn = n & 1023;
  int h = nn >> 6, e = nn & 63;
  Wt[o] = f2bf(W[(h << 16) + (d << 6) + e]);
}

// ---------------- 256x256 8-phase GEMM: C[M][N] = A[M][K] * Bt[N][K]^T, bf16 out ----
// 512 threads = 8 waves (2M x 4N). BK=64, per-wave C = 128x64 (interleaved 16-blocks).
// LDS: [buf][op][half][128*64] bf16 = 128 KiB. T2 chunk swizzle pos = cc ^ (row&7),
// achieved with linear global_load_lds dest + pre-swizzled global source.
// Phase q of K-tile t: quadrant (mh=q>>1, nh=q&1); staging: q0->A1(t+1), q1->B1(t+1),
// q2->A0(t+2), q3->B0(t+2); counted vmcnt(6)/vmcnt(8) at ends of q0/q3 only.
__global__ __launch_bounds__(512, 2) void gemm256_k(const unsigned short* __restrict__ A,
                                                    const unsigned short* __restrict__ Bt,
                                                    unsigned short* __restrict__ C,
                                                    int M, int N, int K) {
  __shared__ __align__(16) unsigned short lds[2][2][2][128 * 64];
  const int tid = threadIdx.x;
  const int wid = tid >> 6, lane = tid & 63;
  const int r = lane & 15, g = lane >> 4;
  const int wm = wid >> 2, wn = wid & 3;

  // XCD-aware bijective swizzle (nwg % 8 == 0)
  int id = blockIdx.y * gridDim.x + blockIdx.x;
  const int cpx = (gridDim.x * gridDim.y) >> 3;
  id = (id & 7) * cpx + (id >> 3);
  const long arow0 = (long)(id % gridDim.x) * 256;
  const long bcol0 = (long)(id / gridDim.x) * 256;

  const f32x4 z4 = {0.f, 0.f, 0.f, 0.f};
  f32x4 acc[8][4];
#pragma unroll
  for (int m = 0; m < 8; ++m)
#pragma unroll
    for (int n = 0; n < 4; ++n) acc[m][n] = z4;

  // stage one half-tile (128 rows x 64 cols) of operand op, half h, K-tile kt
  auto stage_half = [&](int kt, int op, int h) {
    const unsigned short* src = op ? Bt + (bcol0 + 128 * h) * K : A + (arow0 + 128 * h) * K;
    const int k0 = kt << 6;
    unsigned short* base = &lds[kt & 1][op][h][0];
#pragma unroll
    for (int c = 0; c < 2; ++c) {
      const int j = c * 512 + (wid << 6) + lane;  // 16B chunk id 0..1023
      const int row = j >> 3, cc = j & 7;
      const int ccs = cc ^ (row & 7);             // pre-swizzled global source chunk
      gload16(src + (long)row * K + k0 + ccs * 8, base + (c * 512 + (wid << 6)) * 8);
    }
  };

  const int nk = K >> 6;
  // prologue: A0(0),B0(0),A1(0),B1(0),A0(1),B0(1)
  stage_half(0, 0, 0);
  stage_half(0, 1, 0);
  stage_half(0, 0, 1);
  stage_half(0, 1, 1);
  stage_half(1, 0, 0);
  stage_half(1, 1, 0);
  asm volatile("s_waitcnt vmcnt(8)" ::: "memory");
  asm volatile("s_barrier" ::: "memory");

  for (int t = 0; t < nk; ++t) {
    const int buf = t & 1;
#pragma unroll
    for (int ph = 0; ph < 4; ++ph) {
      const int mh = ph >> 1, nh = ph & 1;
      // ds_read this quadrant's fragments (12 x ds_read_b128)
      bf16x8 af[4][2], bfv[2][2];
#pragma unroll
      for (int i = 0; i < 4; ++i)
#pragma unroll
        for (int kk = 0; kk < 2; ++kk) {
          const int rowh = (2 * i + wm) * 16 + r;
          af[i][kk] = *(const bf16x8*)&lds[buf][0][mh][rowh * 64 + (((kk << 2) + g) ^ (rowh & 7)) * 8];
        }
#pragma unroll
      for (int j = 0; j < 2; ++j)
#pragma unroll
        for (int kk = 0; kk < 2; ++kk) {
          const int rowh = (4 * j + wn) * 16 + r;
          bfv[j][kk] = *(const bf16x8*)&lds[buf][1][nh][rowh * 64 + (((kk << 2) + g) ^ (rowh & 7)) * 8];
        }
      // issue this phase's half-tile prefetch
      if (ph == 0) { if (t + 1 < nk) stage_half(t + 1, 0, 1); }
      if (ph == 1) { if (t + 1 < nk) stage_half(t + 1, 1, 1); }
      if (ph == 2) { if (t + 2 < nk) stage_half(t + 2, 0, 0); }
      if (ph == 3) { if (t + 2 < nk) stage_half(t + 2, 1, 0); }
      asm volatile("s_barrier" ::: "memory");
      __builtin_amdgcn_s_setprio(1);
#pragma unroll
      for (int kk = 0; kk < 2; ++kk)
#pragma unroll
        for (int i = 0; i < 4; ++i)
#pragma unroll
          for (int j = 0; j < 2; ++j)
            acc[4 * mh + i][2 * nh + j] = __builtin_amdgcn_mfma_f32_16x16x32_bf16(
                af[i][kk], bfv[j][kk], acc[4 * mh + i][2 * nh + j], 0, 0, 0);
      __builtin_amdgcn_s_setprio(0);
      // counted waits: end of ph0 covers B1(t) (and A1(t)); end of ph3 covers A0/B0(t+1)
      if (ph == 0) {
        if (t + 1 < nk) asm volatile("s_waitcnt vmcnt(6)" ::: "memory");
        else            asm volatile("s_waitcnt vmcnt(0)" ::: "memory");
      }
      if (ph == 3) {
        if (t + 2 < nk)      asm volatile("s_waitcnt vmcnt(8)" ::: "memory");
        else if (t + 1 < nk) asm volatile("s_waitcnt vmcnt(4)" ::: "memory");
      }
      asm volatile("s_waitcnt lgkmcnt(0)\n\ts_barrier" ::: "memory");
    }
  }

#pragma unroll
  for (int m = 0; m < 8; ++m)
#pragma unroll
    for (int n = 0; n < 4; ++n)
#pragma unroll
      for (int rr = 0; rr < 4; ++rr) {
        const long row = arow0 + (2 * m + wm) * 16 + g * 4 + rr;
        const long col = bcol0 + (4 * n + wn) * 16 + r;
        C[row * N + col] = f2bf(acc[m][n][rr]);
      }
}

// ---------------- 128x128 GEMM (out-proj): C[M][N] = A[M][K] * Bt[N][K]^T + bias, f32 out
__global__ __launch_bounds__(256, 2) void gemm_bt_k(const unsigned short* __restrict__ A,
                                                    const unsigned short* __restrict__ Bt,
                                                    float* __restrict__ C,
                                                    const float* __restrict__ bias,
                                                    int M, int N, int K) {
  __shared__ __align__(16) unsigned short lA[2][128 * 64];
  __shared__ __align__(16) unsigned short lB[2][128 * 64];
  const int tid = threadIdx.x;
  const int wid = tid >> 6, lane = tid & 63;
  const int r = lane & 15, g = lane >> 4;
  const long arow0 = (long)blockIdx.x * 128;
  const long brow0 = (long)blockIdx.y * 128;
  const int wr = (wid >> 1) * 64, wc = (wid & 1) * 64;

  const f32x4 z4 = {0.f, 0.f, 0.f, 0.f};
  f32x4 acc[4][4];
#pragma unroll
  for (int m = 0; m < 4; ++m)
#pragma unroll
    for (int n = 0; n < 4; ++n) acc[m][n] = z4;

  auto stage = [&](int buf, int k0) {
#pragma unroll
    for (int c = 0; c < 4; ++c) {
      const int j = c * 256 + wid * 64 + lane;   // 16B chunk id, 0..1023
      const int row = j >> 3, col = (j & 7) * 8; // 8 chunks per 64-elem row
      gload16(A + (arow0 + row) * K + k0 + col, &lA[buf][(c * 256 + wid * 64) * 8]);
      gload16(Bt + (brow0 + row) * K + k0 + col, &lB[buf][(c * 256 + wid * 64) * 8]);
    }
  };

  stage(0, 0);
  __syncthreads();
  const int nk = K >> 6;
  for (int kt = 0; kt < nk; ++kt) {
    const int cur = kt & 1;
    if (kt + 1 < nk) stage(cur ^ 1, (kt + 1) << 6);
#pragma unroll
    for (int kk = 0; kk < 2; ++kk) {
      bf16x8 af[4], bfr[4];
#pragma unroll
      for (int m = 0; m < 4; ++m)
        af[m] = *(const bf16x8*)&lA[cur][(wr + m * 16 + r) * 64 + kk * 32 + g * 8];
#pragma unroll
      for (int n = 0; n < 4; ++n)
        bfr[n] = *(const bf16x8*)&lB[cur][(wc + n * 16 + r) * 64 + kk * 32 + g * 8];
#pragma unroll
      for (int m = 0; m < 4; ++m)
#pragma unroll
        for (int n = 0; n < 4; ++n)
          acc[m][n] = __builtin_amdgcn_mfma_f32_16x16x32_bf16(af[m], bfr[n], acc[m][n], 0, 0, 0);
    }
    __syncthreads();
  }

#pragma unroll
  for (int m = 0; m < 4; ++m) {
#pragma unroll
    for (int n = 0; n < 4; ++n) {
#pragma unroll
      for (int rr = 0; rr < 4; ++rr) {
        const long row = arow0 + wr + m * 16 + g * 4 + rr;
        const long col = brow0 + wc + n * 16 + r;
        C[row * N + col] = acc[m][n][rr] + bias[col];
      }
    }
  }
}

// ---------------- flash attention ----------------
// qkv: [B*S][3072] bf16 (q|k|v each [H=16][HD=64] concat), out: [B*S][1024] bf16
__global__ __launch_bounds__(256, 2) void attn_k(const unsigned short* __restrict__ qkv,
                                                 unsigned short* __restrict__ out) {
  __shared__ __align__(16) unsigned short lK[2][64 * 64];
  __shared__ __align__(16) unsigned short lVt[2][64 * 64];

  const int tid = threadIdx.x, wid = tid >> 6, lane = tid & 63;
  const int r = lane & 15, g = lane >> 4;
  const int bh = blockIdx.x;
  const int b = bh >> 4, h = bh & 15;
  const int qb = 15 - (int)blockIdx.y;   // long blocks dispatch first
  const int q0 = qb * 128;

  const long base = ((long)b * S_) * 3072 + h * 64;
  const unsigned short* Qg = qkv + base;
  const unsigned short* Kg = qkv + base + 1024;
  const unsigned short* Vg = qkv + base + 2048;

  // Q fragments for both subtiles
  int qrow[2];
  bf16x8 qf[2][2];
#pragma unroll
  for (int qs = 0; qs < 2; ++qs) {
    qrow[qs] = q0 + qs * 64 + wid * 16 + r;
#pragma unroll
    for (int kk = 0; kk < 2; ++kk)
      qf[qs][kk] = *(const bf16x8*)&Qg[(long)qrow[qs] * 3072 + kk * 32 + g * 8];
  }

  const f32x4 z4 = {0.f, 0.f, 0.f, 0.f};
  f32x4 o[2][4];
#pragma unroll
  for (int qs = 0; qs < 2; ++qs)
#pragma unroll
    for (int nt = 0; nt < 4; ++nt) o[qs][nt] = z4;
  float m_i[2] = {-1e30f, -1e30f};
  float l_i[2] = {0.f, 0.f};

  // double-buffer staging registers
  u16x8 kreg[2], vreg[2];
  auto load_regs = [&](int t0) {
#pragma unroll
    for (int c = 0; c < 2; ++c) {
      const int j = c * 256 + tid;
      const int tt = j >> 3, e0 = (j & 7) * 8;   // K: row tt, chunk e0/8
      kreg[c] = *(const u16x8*)&Kg[(long)(t0 + tt) * 3072 + e0];
      const int tc = j & 63, ec = j >> 6;        // V: token tc, elems ec*8..
      vreg[c] = *(const u16x8*)&Vg[(long)(t0 + tc) * 3072 + ec * 8];
    }
  };
  auto write_lds = [&](int buf) {
#pragma unroll
    for (int c = 0; c < 2; ++c) {
      const int j = c * 256 + tid;
      const int row = j >> 3, cc = j & 7;
      *(u16x8*)&lK[buf][(row * 8 + (cc ^ (row & 7))) * 8] = kreg[c];
      const int tc = j & 63, ec = j >> 6;
#pragma unroll
      for (int i = 0; i < 8; ++i) {
        const int e = ec * 8 + i;                 // lVt row = feature e, col = token tc
        lVt[buf][e * 64 + (tc ^ (i * 8))] = vreg[c][i];
      }
    }
  };

  const int ntiles = (q0 >> 6) + 2;  // kv tiles 0 .. q0/64+1
  load_regs(0);
  write_lds(0);

  for (int t = 0; t < ntiles; ++t) {
    const int cur = t & 1;
    if (t + 1 < ntiles) load_regs((t + 1) << 6);  // issue early: latency hides under compute
    __syncthreads();                              // LDS[cur] ready; prior reads of cur^1 done

    const int t0 = t << 6;
    const bool act0 = (t < ntiles - 1);   // qs=0 rows all < q0+64
    const bool diag0 = (t == ntiles - 2); // t0 == q0
    const bool diag1 = (t == ntiles - 1); // t0 == q0+64

    // S^T = K Q^T (swapped operands): st[qs][tt][rg] = S[qrow[qs]][t0+16tt+4g+rg]
    f32x4 st[2][4];
#pragma unroll
    for (int tt = 0; tt < 4; ++tt) { st[0][tt] = z4; st[1][tt] = z4; }
    __builtin_amdgcn_s_setprio(1);
#pragma unroll
    for (int kk = 0; kk < 2; ++kk)
#pragma unroll
      for (int tt = 0; tt < 4; ++tt) {
        const int row = tt * 16 + r, cc = kk * 4 + g;
        bf16x8 kf = *(const bf16x8*)&lK[cur][(row * 8 + (cc ^ (row & 7))) * 8];
        st[1][tt] = __builtin_amdgcn_mfma_f32_16x16x32_bf16(kf, qf[1][kk], st[1][tt], 0, 0, 0);
        if (act0)
          st[0][tt] = __builtin_amdgcn_mfma_f32_16x16x32_bf16(kf, qf[0][kk], st[0][tt], 0, 0, 0);
      }
    __builtin_amdgcn_s_setprio(0);

    // per-lane softmax + in-register P repack, per active subtile
    bf16x8 pf[2][2];
    unsigned corr_bits[2] = {0x3f800000u, 0x3f800000u};
    bool dodef[2] = {true, true};
#pragma unroll
    for (int qs = 0; qs < 2; ++qs) {
      if (qs == 0 && !act0) continue;
      const bool diag = qs ? diag1 : diag0;
      float sv[16];
#pragma unroll
      for (int tt = 0; tt < 4; ++tt)
#pragma unroll
        for (int rg = 0; rg < 4; ++rg) {
          float s = st[qs][tt][rg] * 0.125f;  // 1/sqrt(64)
          if (diag && (t0 + tt * 16 + g * 4 + rg > qrow[qs])) s = -1e30f;
          sv[tt * 4 + rg] = s;
        }
      float h0 = fmaxf(fmaxf(fmaxf(sv[0], sv[1]), fmaxf(sv[2], sv[3])),
                       fmaxf(fmaxf(sv[4], sv[5]), fmaxf(sv[6], sv[7])));
      float h1 = fmaxf(fmaxf(fmaxf(sv[8], sv[9]), fmaxf(sv[10], sv[11])),
                       fmaxf(fmaxf(sv[12], sv[13]), fmaxf(sv[14], sv[15])));
      const float pmax = fmaxf(h0, h1);
      const bool defer = __all(pmax - m_i[qs] <= 8.f);  // T13
      float corr = 1.f;
      if (!defer) {
        float mx = fmaxf(pmax, m_i[qs]);
        mx = fmaxf(mx, __shfl_xor(mx, 16, 64));
        mx = fmaxf(mx, __shfl_xor(mx, 32, 64));
        corr = __expf(m_i[qs] - mx);
        m_i[qs] = mx;
      }
      dodef[qs] = defer;
      corr_bits[qs] = __float_as_uint(corr);
      float p[16];
      float rs = 0.f;
#pragma unroll
      for (int i = 0; i < 16; ++i) {
        p[i] = __expf(sv[i] - m_i[qs]);
        rs += p[i];
      }
      rs += __shfl_xor(rs, 16, 64);
      rs += __shfl_xor(rs, 32, 64);
      l_i[qs] = l_i[qs] * corr + rs;
      // pack pairs: c[tt][e] covers kv pair (16tt + 4g + 2e)
      unsigned cw[4][2];
#pragma unroll
      for (int tt = 0; tt < 4; ++tt)
#pragma unroll
        for (int e = 0; e < 2; ++e)
          asm("v_cvt_pk_bf16_f32 %0, %1, %2"
              : "=v"(cw[tt][e]) : "v"(p[tt * 4 + 2 * e]), "v"(p[tt * 4 + 2 * e + 1]));
      // redistribute to A-frag words
#pragma unroll
      for (int kk = 0; kk < 2; ++kk) {
        unsigned x0 = cw[2 * kk][0], y0 = cw[2 * kk + 1][0];
        unsigned x1 = cw[2 * kk][1], y1 = cw[2 * kk + 1][1];
        asm volatile("v_permlane32_swap_b32 %0, %1" : "+v"(x0), "+v"(y0));
        asm volatile("v_permlane16_swap_b32 %0, %1" : "+v"(x0), "+v"(y0));
        asm volatile("v_permlane32_swap_b32 %0, %1" : "+v"(x1), "+v"(y1));
        asm volatile("v_permlane16_swap_b32 %0, %1" : "+v"(x1), "+v"(y1));
        uint4v w = {x0, x1, y0, y1};  // kv pairs (8g+0),(8g+2),(8g+4),(8g+6)
        pf[qs][kk] = *(bf16x8*)&w;
      }
    }
    // O rescale (rows live at lanes r'=4g+rr; corr per-lane at r) — only when needed
#pragma unroll
    for (int qs = 0; qs < 2; ++qs) {
      if (qs == 0 && !act0) continue;
      if (!dodef[qs]) {
        const float corr = __uint_as_float(corr_bits[qs]);
#pragma unroll
        for (int rr = 0; rr < 4; ++rr) {
          const float c = __shfl(corr, g * 4 + rr, 64);
#pragma unroll
          for (int nt = 0; nt < 4; ++nt) o[qs][nt][rr] *= c;
        }
      }
    }

    // O += P V
    __builtin_amdgcn_s_setprio(1);
#pragma unroll
    for (int kk = 0; kk < 2; ++kk)
#pragma unroll
      for (int nt = 0; nt < 4; ++nt) {
        const int row = nt * 16 + r, cc = kk * 4 + g;
        const bf16x8 vf = *(const bf16x8*)&lVt[cur][(row * 8 + (cc ^ (row & 7))) * 8];
        o[1][nt] = __builtin_amdgcn_mfma_f32_16x16x32_bf16(pf[1][kk], vf, o[1][nt], 0, 0, 0);
        if (act0)
          o[0][nt] = __builtin_amdgcn_mfma_f32_16x16x32_bf16(pf[0][kk], vf, o[0][nt], 0, 0, 0);
      }
    __builtin_amdgcn_s_setprio(0);

    if (t + 1 < ntiles) write_lds(cur ^ 1);  // safe: all waves passed this tile's barrier
  }

#pragma unroll
  for (int qs = 0; qs < 2; ++qs) {
    float linv[4];
#pragma unroll
    for (int rr = 0; rr < 4; ++rr)
      linv[rr] = 1.f / __shfl(l_i[qs], g * 4 + rr, 64);
#pragma unroll
    for (int nt = 0; nt < 4; ++nt)
#pragma unroll
      for (int rr = 0; rr < 4; ++rr) {
        const long s = q0 + qs * 64 + wid * 16 + g * 4 + rr;
        out[((long)b * S_ + s) * 1024 + h * 64 + nt * 16 + r] = f2bf(o[qs][nt][rr] * linv[rr]);
      }
  }
}

extern "C" void kernel_launch(void* const* d_in, const int* in_sizes, int n_in,
                              void* d_out, int out_size, void* d_ws, size_t ws_size,
                              hipStream_t stream) {
  const float* x = (const float*)d_in[0];
  const float* Wq = (const float*)d_in[1];
  const float* Wk = (const float*)d_in[2];
  const float* Wv = (const float*)d_in[3];
  const float* Wo = (const float*)d_in[4];
  const float* bo = (const float*)d_in[5];
  float* out = (float*)d_out;

  char* ws = (char*)d_ws;
  unsigned short* Xb = (unsigned short*)(ws);                        // 16 MiB: x bf16 [8192][1024]
  unsigned short* Wt = (unsigned short*)(ws + (16ul << 20));         //  6 MiB: qkv weight B^T [3072][1024]
  unsigned short* Wob = (unsigned short*)(ws + (22ul << 20));        //  2 MiB: Wo bf16 [1024][1024]
  unsigned short* QKV = (unsigned short*)(ws + (24ul << 20));        // 48 MiB: [8192][3072]
  unsigned short* AO = (unsigned short*)(ws + (72ul << 20));         // 16 MiB: attn out [8192][1024]

  pack_x_k<<<2048, 256, 0, stream>>>(x, Xb, (B_ * S_ * D_) / 4);
  pack_x_k<<<512, 256, 0, stream>>>(Wo, Wob, (D_ * D_) / 4);
  pack_wqkv_k<<<(3 * D_ * D_) / 256, 256, 0, stream>>>(Wq, Wk, Wv, Wt);

  gemm256_k<<<dim3(32, 12), 512, 0, stream>>>(Xb, Wt, QKV, B_ * S_, 3 * D_, D_);
  attn_k<<<dim3(64, 16), 256, 0, stream>>>(QKV, AO);
  gemm_bt_k<<<dim3(64, 8), 256, 0, stream>>>(AO, Wob, out, bo, B_ * S_, D_, D_);
}

// Round 6
// 188.495 us; speedup vs baseline: 2.3109x; 1.0572x over previous
//
#include <hip/hip_runtime.h>
#include <hip/hip_bf16.h>

typedef __bf16 bf16x8 __attribute__((ext_vector_type(8)));
typedef float f32x4 __attribute__((ext_vector_type(4)));
typedef unsigned short u16x4 __attribute__((ext_vector_type(4)));
typedef unsigned short u16x8 __attribute__((ext_vector_type(8)));
typedef unsigned uint4v __attribute__((ext_vector_type(4)));

#define B_ 4
#define S_ 2048
#define D_ 1024
#define H_ 16
#define HD_ 64

__device__ __forceinline__ unsigned short f2bf(float f) {
  unsigned u = __float_as_uint(f);
  u += 0x7fff + ((u >> 16) & 1);   // round-to-nearest-even
  return (unsigned short)(u >> 16);
}

__device__ __forceinline__ void gload16(const void* g, void* l) {
  __builtin_amdgcn_global_load_lds((const __attribute__((address_space(1))) unsigned int*)g,
                                   (__attribute__((address_space(3))) unsigned int*)l,
                                   16, 0, 0);
}

// ---------------- pack kernels ----------------
__global__ void pack_x_k(const float* __restrict__ in, unsigned short* __restrict__ out, int n4) {
  int i = blockIdx.x * blockDim.x + threadIdx.x;
  int stride = gridDim.x * blockDim.x;
  for (; i < n4; i += stride) {
    float4 v = reinterpret_cast<const float4*>(in)[i];
    u16x4 o = {f2bf(v.x), f2bf(v.y), f2bf(v.z), f2bf(v.w)};
    reinterpret_cast<u16x4*>(out)[i] = o;
  }
}

// Wq/Wk/Wv [H][D][HD] f32 -> Wt [3*D][D] bf16, Wt[h*64+e (+1024/2048)][d] = W[h][d][e]
__global__ void pack_wqkv_k(const float* __restrict__ Wq, const float* __restrict__ Wk,
                            const float* __restrict__ Wv, unsigned short* __restrict__ Wt) {
  int o = blockIdx.x * blockDim.x + threadIdx.x;  // 0 .. 3*1024*1024-1
  int n = o >> 10;
  int d = o & 1023;
  const float* W = (n < 1024) ? Wq : (n < 2048) ? Wk : Wv;
  int nn = n & 1023;
  int h = nn >> 6, e = nn & 63;
  Wt[o] = f2bf(W[(h << 16) + (d << 6) + e]);
}

// ---------------- 256x256 8-phase GEMM: C[M][N] = A[M][K] * Bt[N][K]^T, bf16 out ----
// 512 threads = 8 waves (2M x 4N). BK=64, per-wave C = 128x64 (interleaved 16-blocks).
// LDS: [buf][op][half][128*64] bf16 = 128 KiB. T2 chunk swizzle pos = cc ^ (row&7),
// via linear global_load_lds dest + pre-swizzled global source.
// Phase order (mh,nh) = (0,0),(0,1),(1,1),(1,0) with persistent reg fragments:
// reads per K-tile = 12+4+8+0 = 24 ds_read_b128 (the necessary minimum).
// Staging: all 4 halves of t+1 during t: A0,B0@ph0; B1@ph1; A1@ph2.
// Counted waits: ph0-end vmcnt(6), ph1-end vmcnt(6), ph3-end vmcnt(4); never 0 mid-loop.
__global__ __launch_bounds__(512, 2) void gemm256_k(const unsigned short* __restrict__ A,
                                                    const unsigned short* __restrict__ Bt,
                                                    unsigned short* __restrict__ C,
                                                    int M, int N, int K) {
  __shared__ __align__(16) unsigned short lds[2][2][2][128 * 64];
  const int tid = threadIdx.x;
  const int wid = tid >> 6, lane = tid & 63;
  const int r = lane & 15, g = lane >> 4;
  const int wm = wid >> 2, wn = wid & 3;

  // XCD-locality map (grid must be 32x12): xcd = hw&7 -> (rx,cx) in 4x2 XCD grid;
  // per-XCD tile block = 8 arows x 6 bcols (A panel 4MB + B panel 3MB ~ fits 4MiB L2).
  const int i_hw = blockIdx.y * gridDim.x + blockIdx.x;
  const int xcd = i_hw & 7, j = i_hw >> 3;
  const long arow0 = (long)((xcd & 3) * 8 + (j & 7)) * 256;
  const long bcol0 = (long)((xcd >> 2) * 6 + (j >> 3)) * 256;

  const f32x4 z4 = {0.f, 0.f, 0.f, 0.f};
  f32x4 acc[8][4];
#pragma unroll
  for (int m = 0; m < 8; ++m)
#pragma unroll
    for (int n = 0; n < 4; ++n) acc[m][n] = z4;

  // stage one half-tile (128 rows x 64 cols) of operand op, half h, K-tile kt
  auto stage_half = [&](int kt, int op, int h) {
    const unsigned short* src = op ? Bt + (bcol0 + 128 * h) * K : A + (arow0 + 128 * h) * K;
    const int k0 = kt << 6;
    unsigned short* base = &lds[kt & 1][op][h][0];
#pragma unroll
    for (int c = 0; c < 2; ++c) {
      const int jj = c * 512 + (wid << 6) + lane;  // 16B chunk id 0..1023
      const int row = jj >> 3, cc = jj & 7;
      const int ccs = cc ^ (row & 7);              // pre-swizzled global source chunk
      gload16(src + (long)row * K + k0 + ccs * 8, base + (c * 512 + (wid << 6)) * 8);
    }
  };

  bf16x8 af[4][2], bv0[2][2], bv1[2][2];
  auto read_a = [&](int buf, int mh) {
#pragma unroll
    for (int i2 = 0; i2 < 4; ++i2)
#pragma unroll
      for (int kk = 0; kk < 2; ++kk) {
        const int rowh = (2 * i2 + wm) * 16 + r;
        af[i2][kk] = *(const bf16x8*)&lds[buf][0][mh][rowh * 64 + (((kk << 2) + g) ^ (rowh & 7)) * 8];
      }
  };
  auto read_b = [&](bf16x8 (&bv)[2][2], int buf, int nh) {
#pragma unroll
    for (int j2 = 0; j2 < 2; ++j2)
#pragma unroll
      for (int kk = 0; kk < 2; ++kk) {
        const int rowh = (4 * j2 + wn) * 16 + r;
        bv[j2][kk] = *(const bf16x8*)&lds[buf][1][nh][rowh * 64 + (((kk << 2) + g) ^ (rowh & 7)) * 8];
      }
  };
  auto mma_q = [&](bf16x8 (&bv)[2][2], int mh, int nh) {
    __builtin_amdgcn_s_setprio(1);
#pragma unroll
    for (int kk = 0; kk < 2; ++kk)
#pragma unroll
      for (int i2 = 0; i2 < 4; ++i2)
#pragma unroll
        for (int j2 = 0; j2 < 2; ++j2)
          acc[4 * mh + i2][2 * nh + j2] = __builtin_amdgcn_mfma_f32_16x16x32_bf16(
              af[i2][kk], bv[j2][kk], acc[4 * mh + i2][2 * nh + j2], 0, 0, 0);
    __builtin_amdgcn_s_setprio(0);
  };

  const int nk = K >> 6;
  // prologue: issue tile 0 halves in steady-state order A0,B0,B1,A1
  stage_half(0, 0, 0);
  stage_half(0, 1, 0);
  stage_half(0, 1, 1);
  stage_half(0, 0, 1);
  asm volatile("s_waitcnt vmcnt(4)" ::: "memory");  // A0(0),B0(0) landed
  asm volatile("s_barrier" ::: "memory");

  for (int t = 0; t < nk; ++t) {
    const int buf = t & 1;
    const bool pre = (t + 1 < nk);
    // ---- phase (0,0): read af0 (8) + bv0 (4); stage A0,B0 of t+1
    read_a(buf, 0);
    read_b(bv0, buf, 0);
    if (pre) { stage_half(t + 1, 0, 0); stage_half(t + 1, 1, 0); }
    asm volatile("s_barrier" ::: "memory");
    mma_q(bv0, 0, 0);
    if (pre) asm volatile("s_waitcnt vmcnt(6)" ::: "memory");   // B1(t) landed
    else     asm volatile("s_waitcnt vmcnt(2)" ::: "memory");
    asm volatile("s_waitcnt lgkmcnt(0)\n\ts_barrier" ::: "memory");
    // ---- phase (0,1): read bv1 (4); stage B1 of t+1
    read_b(bv1, buf, 1);
    if (pre) stage_half(t + 1, 1, 1);
    asm volatile("s_barrier" ::: "memory");
    mma_q(bv1, 0, 1);
    if (pre) asm volatile("s_waitcnt vmcnt(6)" ::: "memory");   // A1(t) landed
    else     asm volatile("s_waitcnt vmcnt(0)" ::: "memory");
    asm volatile("s_waitcnt lgkmcnt(0)\n\ts_barrier" ::: "memory");
    // ---- phase (1,1): read af1 (8); stage A1 of t+1
    read_a(buf, 1);
    if (pre) stage_half(t + 1, 0, 1);
    asm volatile("s_barrier" ::: "memory");
    mma_q(bv1, 1, 1);
    asm volatile("s_waitcnt lgkmcnt(0)\n\ts_barrier" ::: "memory");
    // ---- phase (1,0): pure MFMA (af1 x bv0 from registers)
    asm volatile("s_barrier" ::: "memory");
    mma_q(bv0, 1, 0);
    if (pre) asm volatile("s_waitcnt vmcnt(4)" ::: "memory");   // A0,B0 of t+1 landed
    asm volatile("s_waitcnt lgkmcnt(0)\n\ts_barrier" ::: "memory");
  }

#pragma unroll
  for (int m = 0; m < 8; ++m)
#pragma unroll
    for (int n = 0; n < 4; ++n)
#pragma unroll
      for (int rr = 0; rr < 4; ++rr) {
        const long row = arow0 + (2 * m + wm) * 16 + g * 4 + rr;
        const long col = bcol0 + (4 * n + wn) * 16 + r;
        C[row * N + col] = f2bf(acc[m][n][rr]);
      }
}

// ---------------- 128x128 GEMM (out-proj): C[M][N] = A[M][K] * Bt[N][K]^T + bias, f32 out
__global__ __launch_bounds__(256, 2) void gemm_bt_k(const unsigned short* __restrict__ A,
                                                    const unsigned short* __restrict__ Bt,
                                                    float* __restrict__ C,
                                                    const float* __restrict__ bias,
                                                    int M, int N, int K) {
  __shared__ __align__(16) unsigned short lA[2][128 * 64];
  __shared__ __align__(16) unsigned short lB[2][128 * 64];
  const int tid = threadIdx.x;
  const int wid = tid >> 6, lane = tid & 63;
  const int r = lane & 15, g = lane >> 4;
  const long arow0 = (long)blockIdx.x * 128;
  const long brow0 = (long)blockIdx.y * 128;
  const int wr = (wid >> 1) * 64, wc = (wid & 1) * 64;

  const f32x4 z4 = {0.f, 0.f, 0.f, 0.f};
  f32x4 acc[4][4];
#pragma unroll
  for (int m = 0; m < 4; ++m)
#pragma unroll
    for (int n = 0; n < 4; ++n) acc[m][n] = z4;

  auto stage = [&](int buf, int k0) {
#pragma unroll
    for (int c = 0; c < 4; ++c) {
      const int j = c * 256 + wid * 64 + lane;   // 16B chunk id, 0..1023
      const int row = j >> 3, col = (j & 7) * 8; // 8 chunks per 64-elem row
      gload16(A + (arow0 + row) * K + k0 + col, &lA[buf][(c * 256 + wid * 64) * 8]);
      gload16(Bt + (brow0 + row) * K + k0 + col, &lB[buf][(c * 256 + wid * 64) * 8]);
    }
  };

  stage(0, 0);
  __syncthreads();
  const int nk = K >> 6;
  for (int kt = 0; kt < nk; ++kt) {
    const int cur = kt & 1;
    if (kt + 1 < nk) stage(cur ^ 1, (kt + 1) << 6);
#pragma unroll
    for (int kk = 0; kk < 2; ++kk) {
      bf16x8 af[4], bfr[4];
#pragma unroll
      for (int m = 0; m < 4; ++m)
        af[m] = *(const bf16x8*)&lA[cur][(wr + m * 16 + r) * 64 + kk * 32 + g * 8];
#pragma unroll
      for (int n = 0; n < 4; ++n)
        bfr[n] = *(const bf16x8*)&lB[cur][(wc + n * 16 + r) * 64 + kk * 32 + g * 8];
#pragma unroll
      for (int m = 0; m < 4; ++m)
#pragma unroll
        for (int n = 0; n < 4; ++n)
          acc[m][n] = __builtin_amdgcn_mfma_f32_16x16x32_bf16(af[m], bfr[n], acc[m][n], 0, 0, 0);
    }
    __syncthreads();
  }

#pragma unroll
  for (int m = 0; m < 4; ++m) {
#pragma unroll
    for (int n = 0; n < 4; ++n) {
#pragma unroll
      for (int rr = 0; rr < 4; ++rr) {
        const long row = arow0 + wr + m * 16 + g * 4 + rr;
        const long col = brow0 + wc + n * 16 + r;
        C[row * N + col] = acc[m][n][rr] + bias[col];
      }
    }
  }
}

// ---------------- flash attention ----------------
// qkv: [B*S][3072] bf16 (q|k|v each [H=16][HD=64] concat), out: [B*S][1024] bf16
__global__ __launch_bounds__(256, 2) void attn_k(const unsigned short* __restrict__ qkv,
                                                 unsigned short* __restrict__ out) {
  __shared__ __align__(16) unsigned short lK[2][64 * 64];
  __shared__ __align__(16) unsigned short lVt[2][64 * 64];

  const int tid = threadIdx.x, wid = tid >> 6, lane = tid & 63;
  const int r = lane & 15, g = lane >> 4;
  const int bh = blockIdx.x;
  const int b = bh >> 4, h = bh & 15;
  const int qb = 15 - (int)blockIdx.y;   // long blocks dispatch first
  const int q0 = qb * 128;

  const long base = ((long)b * S_) * 3072 + h * 64;
  const unsigned short* Qg = qkv + base;
  const unsigned short* Kg = qkv + base + 1024;
  const unsigned short* Vg = qkv + base + 2048;

  // Q fragments for both subtiles
  int qrow[2];
  bf16x8 qf[2][2];
#pragma unroll
  for (int qs = 0; qs < 2; ++qs) {
    qrow[qs] = q0 + qs * 64 + wid * 16 + r;
#pragma unroll
    for (int kk = 0; kk < 2; ++kk)
      qf[qs][kk] = *(const bf16x8*)&Qg[(long)qrow[qs] * 3072 + kk * 32 + g * 8];
  }

  const f32x4 z4 = {0.f, 0.f, 0.f, 0.f};
  f32x4 o[2][4];
#pragma unroll
  for (int qs = 0; qs < 2; ++qs)
#pragma unroll
    for (int nt = 0; nt < 4; ++nt) o[qs][nt] = z4;
  float m_i[2] = {-1e30f, -1e30f};
  float l_i[2] = {0.f, 0.f};

  // double-buffer staging registers
  u16x8 kreg[2], vreg[2];
  auto load_regs = [&](int t0) {
#pragma unroll
    for (int c = 0; c < 2; ++c) {
      const int j = c * 256 + tid;
      const int tt = j >> 3, e0 = (j & 7) * 8;   // K: row tt, chunk e0/8
      kreg[c] = *(const u16x8*)&Kg[(long)(t0 + tt) * 3072 + e0];
      const int tc = j & 63, ec = j >> 6;        // V: token tc, elems ec*8..
      vreg[c] = *(const u16x8*)&Vg[(long)(t0 + tc) * 3072 + ec * 8];
    }
  };
  auto write_lds = [&](int buf) {
#pragma unroll
    for (int c = 0; c < 2; ++c) {
      const int j = c * 256 + tid;
      const int row = j >> 3, cc = j & 7;
      *(u16x8*)&lK[buf][(row * 8 + (cc ^ (row & 7))) * 8] = kreg[c];
      const int tc = j & 63, ec = j >> 6;
#pragma unroll
      for (int i = 0; i < 8; ++i) {
        const int e = ec * 8 + i;                 // lVt row = feature e, col = token tc
        lVt[buf][e * 64 + (tc ^ (i * 8))] = vreg[c][i];
      }
    }
  };

  const int ntiles = (q0 >> 6) + 2;  // kv tiles 0 .. q0/64+1
  load_regs(0);
  write_lds(0);

  for (int t = 0; t < ntiles; ++t) {
    const int cur = t & 1;
    if (t + 1 < ntiles) load_regs((t + 1) << 6);  // issue early: latency hides under compute
    __syncthreads();                              // LDS[cur] ready; prior reads of cur^1 done

    const int t0 = t << 6;
    const bool act0 = (t < ntiles - 1);   // qs=0 rows all < q0+64
    const bool diag0 = (t == ntiles - 2); // t0 == q0
    const bool diag1 = (t == ntiles - 1); // t0 == q0+64

    // S^T = K Q^T (swapped operands): st[qs][tt][rg] = S[qrow[qs]][t0+16tt+4g+rg]
    f32x4 st[2][4];
#pragma unroll
    for (int tt = 0; tt < 4; ++tt) { st[0][tt] = z4; st[1][tt] = z4; }
    __builtin_amdgcn_s_setprio(1);
#pragma unroll
    for (int kk = 0; kk < 2; ++kk)
#pragma unroll
      for (int tt = 0; tt < 4; ++tt) {
        const int row = tt * 16 + r, cc = kk * 4 + g;
        bf16x8 kf = *(const bf16x8*)&lK[cur][(row * 8 + (cc ^ (row & 7))) * 8];
        st[1][tt] = __builtin_amdgcn_mfma_f32_16x16x32_bf16(kf, qf[1][kk], st[1][tt], 0, 0, 0);
        if (act0)
          st[0][tt] = __builtin_amdgcn_mfma_f32_16x16x32_bf16(kf, qf[0][kk], st[0][tt], 0, 0, 0);
      }
    __builtin_amdgcn_s_setprio(0);

    // per-lane softmax + in-register P repack, per active subtile
    bf16x8 pf[2][2];
    unsigned corr_bits[2] = {0x3f800000u, 0x3f800000u};
    bool dodef[2] = {true, true};
#pragma unroll
    for (int qs = 0; qs < 2; ++qs) {
      if (qs == 0 && !act0) continue;
      const bool diag = qs ? diag1 : diag0;
      float sv[16];
#pragma unroll
      for (int tt = 0; tt < 4; ++tt)
#pragma unroll
        for (int rg = 0; rg < 4; ++rg) {
          float s = st[qs][tt][rg] * 0.125f;  // 1/sqrt(64)
          if (diag && (t0 + tt * 16 + g * 4 + rg > qrow[qs])) s = -1e30f;
          sv[tt * 4 + rg] = s;
        }
      float h0 = fmaxf(fmaxf(fmaxf(sv[0], sv[1]), fmaxf(sv[2], sv[3])),
                       fmaxf(fmaxf(sv[4], sv[5]), fmaxf(sv[6], sv[7])));
      float h1 = fmaxf(fmaxf(fmaxf(sv[8], sv[9]), fmaxf(sv[10], sv[11])),
                       fmaxf(fmaxf(sv[12], sv[13]), fmaxf(sv[14], sv[15])));
      const float pmax = fmaxf(h0, h1);
      const bool defer = __all(pmax - m_i[qs] <= 8.f);  // T13
      float corr = 1.f;
      if (!defer) {
        float mx = fmaxf(pmax, m_i[qs]);
        mx = fmaxf(mx, __shfl_xor(mx, 16, 64));
        mx = fmaxf(mx, __shfl_xor(mx, 32, 64));
        corr = __expf(m_i[qs] - mx);
        m_i[qs] = mx;
      }
      dodef[qs] = defer;
      corr_bits[qs] = __float_as_uint(corr);
      float p[16];
      float rs = 0.f;
#pragma unroll
      for (int i = 0; i < 16; ++i) {
        p[i] = __expf(sv[i] - m_i[qs]);
        rs += p[i];
      }
      rs += __shfl_xor(rs, 16, 64);
      rs += __shfl_xor(rs, 32, 64);
      l_i[qs] = l_i[qs] * corr + rs;
      // pack pairs: c[tt][e] covers kv pair (16tt + 4g + 2e)
      unsigned cw[4][2];
#pragma unroll
      for (int tt = 0; tt < 4; ++tt)
#pragma unroll
        for (int e = 0; e < 2; ++e)
          asm("v_cvt_pk_bf16_f32 %0, %1, %2"
              : "=v"(cw[tt][e]) : "v"(p[tt * 4 + 2 * e]), "v"(p[tt * 4 + 2 * e + 1]));
      // redistribute to A-frag words
#pragma unroll
      for (int kk = 0; kk < 2; ++kk) {
        unsigned x0 = cw[2 * kk][0], y0 = cw[2 * kk + 1][0];
        unsigned x1 = cw[2 * kk][1], y1 = cw[2 * kk + 1][1];
        asm volatile("v_permlane32_swap_b32 %0, %1" : "+v"(x0), "+v"(y0));
        asm volatile("v_permlane16_swap_b32 %0, %1" : "+v"(x0), "+v"(y0));
        asm volatile("v_permlane32_swap_b32 %0, %1" : "+v"(x1), "+v"(y1));
        asm volatile("v_permlane16_swap_b32 %0, %1" : "+v"(x1), "+v"(y1));
        uint4v w = {x0, x1, y0, y1};  // kv pairs (8g+0),(8g+2),(8g+4),(8g+6)
        pf[qs][kk] = *(bf16x8*)&w;
      }
    }
    // O rescale (rows live at lanes r'=4g+rr; corr per-lane at r) — only when needed
#pragma unroll
    for (int qs = 0; qs < 2; ++qs) {
      if (qs == 0 && !act0) continue;
      if (!dodef[qs]) {
        const float corr = __uint_as_float(corr_bits[qs]);
#pragma unroll
        for (int rr = 0; rr < 4; ++rr) {
          const float c = __shfl(corr, g * 4 + rr, 64);
#pragma unroll
          for (int nt = 0; nt < 4; ++nt) o[qs][nt][rr] *= c;
        }
      }
    }

    // O += P V
    __builtin_amdgcn_s_setprio(1);
#pragma unroll
    for (int kk = 0; kk < 2; ++kk)
#pragma unroll
      for (int nt = 0; nt < 4; ++nt) {
        const int row = nt * 16 + r, cc = kk * 4 + g;
        const bf16x8 vf = *(const bf16x8*)&lVt[cur][(row * 8 + (cc ^ (row & 7))) * 8];
        o[1][nt] = __builtin_amdgcn_mfma_f32_16x16x32_bf16(pf[1][kk], vf, o[1][nt], 0, 0, 0);
        if (act0)
          o[0][nt] = __builtin_amdgcn_mfma_f32_16x16x32_bf16(pf[0][kk], vf, o[0][nt], 0, 0, 0);
      }
    __builtin_amdgcn_s_setprio(0);

    if (t + 1 < ntiles) write_lds(cur ^ 1);  // safe: all waves passed this tile's barrier
  }

#pragma unroll
  for (int qs = 0; qs < 2; ++qs) {
    float linv[4];
#pragma unroll
    for (int rr = 0; rr < 4; ++rr)
      linv[rr] = 1.f / __shfl(l_i[qs], g * 4 + rr, 64);
#pragma unroll
    for (int nt = 0; nt < 4; ++nt)
#pragma unroll
      for (int rr = 0; rr < 4; ++rr) {
        const long s = q0 + qs * 64 + wid * 16 + g * 4 + rr;
        out[((long)b * S_ + s) * 1024 + h * 64 + nt * 16 + r] = f2bf(o[qs][nt][rr] * linv[rr]);
      }
  }
}

extern "C" void kernel_launch(void* const* d_in, const int* in_sizes, int n_in,
                              void* d_out, int out_size, void* d_ws, size_t ws_size,
                              hipStream_t stream) {
  const float* x = (const float*)d_in[0];
  const float* Wq = (const float*)d_in[1];
  const float* Wk = (const float*)d_in[2];
  const float* Wv = (const float*)d_in[3];
  const float* Wo = (const float*)d_in[4];
  const float* bo = (const float*)d_in[5];
  float* out = (float*)d_out;

  char* ws = (char*)d_ws;
  unsigned short* Xb = (unsigned short*)(ws);                        // 16 MiB: x bf16 [8192][1024]
  unsigned short* Wt = (unsigned short*)(ws + (16ul << 20));         //  6 MiB: qkv weight B^T [3072][1024]
  unsigned short* Wob = (unsigned short*)(ws + (22ul << 20));        //  2 MiB: Wo bf16 [1024][1024]
  unsigned short* QKV = (unsigned short*)(ws + (24ul << 20));        // 48 MiB: [8192][3072]
  unsigned short* AO = (unsigned short*)(ws + (72ul << 20));         // 16 MiB: attn out [8192][1024]

  pack_x_k<<<2048, 256, 0, stream>>>(x, Xb, (B_ * S_ * D_) / 4);
  pack_x_k<<<512, 256, 0, stream>>>(Wo, Wob, (D_ * D_) / 4);
  pack_wqkv_k<<<(3 * D_ * D_) / 256, 256, 0, stream>>>(Wq, Wk, Wv, Wt);

  gemm256_k<<<dim3(32, 12), 512, 0, stream>>>(Xb, Wt, QKV, B_ * S_, 3 * D_, D_);
  attn_k<<<dim3(64, 16), 256, 0, stream>>>(QKV, AO);
  gemm_bt_k<<<dim3(64, 8), 256, 0, stream>>>(AO, Wob, out, bo, B_ * S_, D_, D_);
}